// Round 12
// baseline (270.876 us; speedup 1.0000x reference)
//
#include <hip/hip_runtime.h>

typedef _Float16 f16;
typedef f16   f16x8 __attribute__((ext_vector_type(8)));
typedef f16   f16x4 __attribute__((ext_vector_type(4)));
typedef float f32x4 __attribute__((ext_vector_type(4)));

namespace {
constexpr int kB  = 8;
constexpr int kS  = 1024;
constexpr int kH  = 1024;
constexpr int kNH = 16;
constexpr int kHD = 64;
constexpr int kBH = kB * kNH;            // 128
constexpr int kRows = kBH * kS;          // 131072
constexpr float kLog2e = 1.44269504088896f;
}

// Raw hardware 2^x (v_exp_f32).  Round-9 lesson: plain exp2f lowers to the
// OCML precise version (denormal fixup, ~8 ops + branch) without fast-math;
// __expf is the native 2-op path.
__device__ __forceinline__ float fast_exp2(float x) {
#if __has_builtin(__builtin_amdgcn_exp2f)
    return __builtin_amdgcn_exp2f(x);
#else
    return __expf(x * 0.693147180559945f);   // exp(x*ln2) == 2^x, native path
#endif
}

// async global->LDS, 16B per lane; LDS dest = wave-uniform base + lane*16.
// NOTE: only offset=0 is used — the offset immediate's LDS-vs-global
// semantics are unverified on gfx950 (round-4 NaN post-mortem).
__device__ __forceinline__ void async16(const f16* g, f16* l) {
    __builtin_amdgcn_global_load_lds(
        (const __attribute__((address_space(1))) unsigned int*)g,
        (__attribute__((address_space(3))) unsigned int*)l, 16, 0, 0);
}

// --- LDS chunk swizzles (16B chunks). Uniform bank-slot histogram per quad
// for MFMA fragment reads; invertible for global_load_lds staging. ---
__device__ __forceinline__ int phys4(int m, int c) {
    return ((m >> 1) << 3) | ((((m & 1) << 2) | c) ^ ((m >> 1) & 7));
}
__device__ __forceinline__ int phys8(int m, int c) {
    return (m << 3) | (c ^ (m & 7));
}

// ---------------------------------------------------------------------------
// ALL preprocessing in ONE launch (round 13).
//   blocks [0,8192):    cast hs (y=0) / ce (y=1) fp32 -> f16
//   blocks [8192,8960): transpose Wq/Wk/Wv fp32 [K][N] -> f16 [N][K]
//   blocks [8960,8970): Wcq/Wck transpose-cast + kn zero + mask max
// ---------------------------------------------------------------------------
__global__ __launch_bounds__(256) void prep_all_kernel(
    const float* __restrict__ hs, const float* __restrict__ ce,
    const float* __restrict__ Wq, const float* __restrict__ Wk,
    const float* __restrict__ Wv, const float* __restrict__ Wcq,
    const float* __restrict__ Wck, const float* __restrict__ mask,
    f16* __restrict__ hs16, f16* __restrict__ ce16, f16* __restrict__ Wt,
    f16* __restrict__ Wct, unsigned int* __restrict__ kn,
    float* __restrict__ mm)
{
    const int id = blockIdx.x;
    const int t = threadIdx.x;
    __shared__ f16 T[64][72];
    __shared__ float red[4];

    if (id < 8192) {
        // ---- input casts: y=0 hs flat; y=1 ce head-split ----
        const int x = id & 4095, y = id >> 12;
        int i = (x * 256 + t) * 8;
        const float* src = y ? ce : hs;
        float4 a = *(const float4*)(src + i);
        float4 b = *(const float4*)(src + i + 4);
        union { f16 h[8]; uint4 u; } pk;
        pk.h[0] = (f16)a.x; pk.h[1] = (f16)a.y; pk.h[2] = (f16)a.z; pk.h[3] = (f16)a.w;
        pk.h[4] = (f16)b.x; pk.h[5] = (f16)b.y; pk.h[6] = (f16)b.z; pk.h[7] = (f16)b.w;
        if (y == 0) {
            *(uint4*)(hs16 + i) = pk.u;
        } else {
            int row = i >> 10, col = i & 1023;
            int bb = row >> 10, s = row & 1023;
            int h = col >> 6, d = col & 63;
            size_t o = ((((size_t)(bb * kNH + h) << 10) | s) << 6) | d;
            *(uint4*)(ce16 + o) = pk.u;
        }
    } else if (id < 8960) {
        // ---- W transpose+cast ----
        const int tt = id - 8192;
        const int bx = tt & 15, by = (tt >> 4) & 15, bz = tt >> 8;
        const float* W = (bz == 0) ? Wq : (bz == 1) ? Wk : Wv;
        f16* out = Wt + (size_t)bz * kH * kH;
        const int k0 = by * 64, n0 = bx * 64;
#pragma unroll
        for (int i = 0; i < 4; ++i) {
            int idx = t + i * 256;
            int r = idx >> 4, cb = (idx & 15) * 4;
            float4 v = *(const float4*)(W + (size_t)(k0 + r) * kH + n0 + cb);
            T[cb + 0][r] = (f16)v.x; T[cb + 1][r] = (f16)v.y;
            T[cb + 2][r] = (f16)v.z; T[cb + 3][r] = (f16)v.w;
        }
        __syncthreads();
#pragma unroll
        for (int i = 0; i < 4; ++i) {
            int idx = t + i * 256;
            int r = idx >> 4, cb = (idx & 15) * 4;
            union { f16 h[4]; uint2 u; } pk;
#pragma unroll
            for (int j = 0; j < 4; ++j) pk.h[j] = T[r][cb + j];
            *(uint2*)(out + (size_t)(n0 + r) * kH + k0 + cb) = pk.u;
        }
    } else {
        // ---- small prep ----
        const int bx = id - 8960;
        if (bx < 2) {
            const float* W = bx ? Wck : Wcq;
            f16* out = Wct + bx * kHD * kHD;
#pragma unroll
            for (int i = 0; i < 16; ++i) {
                int idx = i * 256 + t;
                int k = idx >> 6, n = idx & 63;
                out[n * 64 + k] = (f16)W[idx];
            }
            if (bx == 0 && t < kBH) kn[t] = 0u;
        } else {
            const int b = bx - 2;
            const float* mp = mask + b * kS;
            float v = fmaxf(fmaxf(mp[t], mp[t + 256]), fmaxf(mp[t + 512], mp[t + 768]));
#pragma unroll
            for (int off = 1; off < 64; off <<= 1) v = fmaxf(v, __shfl_xor(v, off, 64));
            if ((t & 63) == 0) red[t >> 6] = v;
            __syncthreads();
            if (t == 0) mm[b] = fmaxf(fmaxf(red[0], red[1]), fmaxf(red[2], red[3]));
        }
    }
}

// ---------------------------------------------------------------------------
// QKV GEMM + FUSED CONTEXT GATING (round 16).  Round 17: XB epilogue tile
// XOR-swizzled (block' = block ^ (row&7)) — the scalar f16 blend writes had
// all 4 quads on one bank (4-way); swizzle makes it 2-way (free, m136).
// ---------------------------------------------------------------------------
__global__ __launch_bounds__(256, 3) void qkv_gemm_f16(
    const f16* __restrict__ hs16, const f16* __restrict__ Wt,
    const float* __restrict__ bq, const float* __restrict__ bk,
    const float* __restrict__ bv,
    f16* __restrict__ q16, f16* __restrict__ k16, f16* __restrict__ vt,
    const f16* __restrict__ ce16, const f16* __restrict__ Wct,
    const float* __restrict__ bcq, const float* __restrict__ bck,
    const float* __restrict__ wlqc, const float* __restrict__ wlqq,
    const float* __restrict__ wlkc, const float* __restrict__ wlkk,
    unsigned int* __restrict__ kn)
{
    const int z = blockIdx.z;
    const f16* Bmat = Wt + (size_t)z * kH * kH;
    const float* bias = (z == 0) ? bq : (z == 1) ? bk : bv;

    __shared__ f16 AB[2][2][128 * 32];   // [buf][A=0/B=1]

    const int tid = threadIdx.x;
    const int w = tid >> 6, lane = tid & 63;
    const int quad = lane >> 4, mh = lane & 15;
    const int wm = w >> 1, wn = w & 1;
    const int m0 = blockIdx.x * 128, n0 = blockIdx.y * 128;

    // A staging pointers (per-lane); B address = A address + block-uniform delta
    const f16* aptr[2];
#pragma unroll
    for (int i = 0; i < 2; ++i) {
        int P = (w * 2 + i) * 64 + lane;
        int r2 = P >> 3, s = P & 7;
        int bb = s ^ (r2 & 7);
        int m = (r2 << 1) | (bb >> 2), c = bb & 3;
        aptr[i] = hs16 + (size_t)(m0 + m) * kH + c * 8;
    }
    const ptrdiff_t bdelta = (Bmat + (size_t)n0 * kH) - (hs16 + (size_t)m0 * kH);

    auto issue = [&](int buf) {
#pragma unroll
        for (int i = 0; i < 2; ++i) {
            async16(aptr[i], AB[buf][0] + (w * 2 + i) * 512);
            async16(aptr[i] + bdelta, AB[buf][1] + (w * 2 + i) * 512);
            aptr[i] += 32;
        }
    };

    f32x4 acc[4][4];
#pragma unroll
    for (int i = 0; i < 4; ++i)
#pragma unroll
        for (int j = 0; j < 4; ++j) acc[i][j] = (f32x4){0.f, 0.f, 0.f, 0.f};

    // fragment base offsets; tile t adds +512 elements (phys4 linearity)
    const int aoff0 = phys4(wm * 64 + mh, quad) * 8;
    const int boff0 = phys4(wn * 64 + mh, quad) * 8;

    auto compute = [&](int buf) {
        f16x8 af[4], bf[4];
#pragma unroll
        for (int t = 0; t < 4; ++t)
            af[t] = *(const f16x8*)(AB[buf][0] + aoff0 + t * 512);
#pragma unroll
        for (int t = 0; t < 4; ++t)
            bf[t] = *(const f16x8*)(AB[buf][1] + boff0 + t * 512);
#pragma unroll
        for (int i = 0; i < 4; ++i)
#pragma unroll
            for (int j = 0; j < 4; ++j)
                acc[i][j] = __builtin_amdgcn_mfma_f32_16x16x32_f16(
                    af[i], bf[j], acc[i][j], 0, 0, 0);
    };

    issue(0);                 // tile 0
    __syncthreads();

    for (int it = 0; it < 16; ++it) {
        issue(1);             // prefetch tile 2it+1 (overlaps compute)
        compute(0);           // tile 2it
        __syncthreads();      // drain prefetch; buf0 free
        if (it < 15) issue(0);  // prefetch tile 2it+2
        compute(1);           // tile 2it+1
        __syncthreads();
    }

    if (z < 2) {
        // ---- fused gate epilogue (all same-wave; AB is dead -> XB alias) ----
        f16* outp = (z == 0) ? q16 : k16;
        const float* bc   = (z == 0) ? bcq  : bck;
        const float* wlc  = (z == 0) ? wlqc : wlkc;
        const float* wlxp = (z == 0) ? wlqq : wlkk;
        const int h   = (n0 + wn * 64) >> 6;
        const int bbb = m0 >> 10;
        const int sb  = (m0 & 1023) + wm * 64;
        const size_t rowbase = (size_t)(bbb * kNH + h) * kS + sb;
        f16* base = outp + rowbase * kHD;
        const f16* ceb = ce16 + rowbase * kHD;
        const f16* Wcg = Wct + (size_t)z * kHD * kHD;

        float bnv[4], bcv[4], wlcv[4], wlxv[4];
#pragma unroll
        for (int nt = 0; nt < 4; ++nt) {
            bnv[nt]  = bias[n0 + wn * 64 + nt * 16 + mh];
            const int d = nt * 16 + mh;
            bcv[nt]  = bc[d];
            wlcv[nt] = wlc[d];
            wlxv[nt] = wlxp[d];
        }
        // B fragments for the ce GEMM (L2-hot 16 KB table; round-14 pattern)
        f16x8 bfr[4][2];
#pragma unroll
        for (int nt = 0; nt < 4; ++nt)
#pragma unroll
            for (int ks = 0; ks < 2; ++ks)
                bfr[nt][ks] = *(const f16x8*)(
                    Wcg + (nt * 16 + mh) * 64 + (ks * 4 + quad) * 8);

        f16* XB = &AB[0][0][0] + w * 4096;   // per-wave 64x64 gated tile

#pragma unroll
        for (int mt = 0; mt < 4; ++mt) {
            const f16* cerow = ceb + (size_t)(mt * 16 + mh) * kHD;
            f16x8 a0 = *(const f16x8*)(cerow + quad * 8);
            f16x8 a1 = *(const f16x8*)(cerow + 32 + quad * 8);
            f32x4 accce[4];
#pragma unroll
            for (int nt = 0; nt < 4; ++nt) {
                accce[nt] = __builtin_amdgcn_mfma_f32_16x16x32_f16(
                    a0, bfr[nt][0], (f32x4){0.f, 0.f, 0.f, 0.f}, 0, 0, 0);
                accce[nt] = __builtin_amdgcn_mfma_f32_16x16x32_f16(
                    a1, bfr[nt][1], accce[nt], 0, 0, 0);
            }
#pragma unroll
            for (int r = 0; r < 4; ++r) {
                f16 x16[4], cq16[4];
                float t = 0.f;
#pragma unroll
                for (int nt = 0; nt < 4; ++nt) {
                    x16[nt] = (f16)(acc[mt][nt][r] + bnv[nt]);
                    const float vq = accce[nt][r] + bcv[nt];
                    cq16[nt] = (f16)vq;
                    t += (float)x16[nt] * wlxv[nt] + vq * wlcv[nt];
                }
                t += __shfl_xor(t, 1, 64);
                t += __shfl_xor(t, 2, 64);
                t += __shfl_xor(t, 4, 64);
                t += __shfl_xor(t, 8, 64);
                const float lam = 1.0f / (1.0f + __expf(-t));
                const int row = mt * 16 + quad * 4 + r;
#pragma unroll
                for (int nt = 0; nt < 4; ++nt) {
                    const int blk = (nt * 2 + (mh >> 3)) ^ (row & 7);
                    XB[row * 64 + (blk << 3) + (mh & 7)] =
                        (f16)((1.0f - lam) * (float)x16[nt] +
                              lam * (float)cq16[nt]);
                }
            }
        }
        // coalesced store (+ z==1: per-row |k|^2 max -> kn[bh])
        float wmax = 0.f;
#pragma unroll
        for (int p = 0; p < 8; ++p) {
            const int row = (lane >> 3) + p * 8;
            const int blk = (lane & 7) ^ (row & 7);
            union { uint4 u; f16 hh[8]; } v;
            v.u = *(const uint4*)(XB + row * 64 + (blk << 3));
            *(uint4*)(base + (size_t)row * kHD + (lane & 7) * 8) = v.u;
            if (z == 1) {
                float ss = 0.f;
#pragma unroll
                for (int j = 0; j < 8; ++j) {
                    const float f = (float)v.hh[j];
                    ss += f * f;
                }
                ss += __shfl_xor(ss, 1, 64);
                ss += __shfl_xor(ss, 2, 64);
                ss += __shfl_xor(ss, 4, 64);
                wmax = fmaxf(wmax, ss);
            }
        }
        if (z == 1) {
            wmax = fmaxf(wmax, __shfl_xor(wmax, 8, 64));
            wmax = fmaxf(wmax, __shfl_xor(wmax, 16, 64));
            wmax = fmaxf(wmax, __shfl_xor(wmax, 32, 64));
            if (lane == 0) atomicMax(&kn[bbb * kNH + h], __float_as_uint(wmax));
        }
    } else {
#pragma unroll
        for (int nt = 0; nt < 4; ++nt) {
            const int n = n0 + wn * 64 + nt * 16 + mh;
            const int h = n >> 6, d = n & 63;
            const float bn = bias[n];
#pragma unroll
            for (int mt = 0; mt < 4; ++mt) {
                int mbase = m0 + wm * 64 + mt * 16 + quad * 4;
                int bbb = mbase >> 10, s0 = mbase & 1023;
                union { f16 h4[4]; uint2 u; } pk;
#pragma unroll
                for (int r = 0; r < 4; ++r) pk.h4[r] = (f16)(acc[mt][nt][r] + bn);
                *(uint2*)(vt + ((size_t)(bbb * kNH + h) * kHD + d) * kS + s0) = pk.u;
            }
        }
    }
}

// ---------------------------------------------------------------------------
// MFMA flash attention.  Round 17: K-fragments loaded ONCE per step (both
// rt share identical kf) — QK for rt0 and rt1 computed per-nt from one
// load pair; rt1's P parks packed in 4 uint2 regs (+8 VGPRs) and is
// written to Pt right after rt0's tr-read drains, so the ds_writes overlap
// rt0's register-only PV MFMAs.  kf ds_read_b128: 16 -> 8 per step; rt1's
// QK stall removed.  Same math, same buffers, same barriers.
// ---------------------------------------------------------------------------
__global__ __launch_bounds__(256, 4) void attn_f16(
    const f16* __restrict__ q16, const f16* __restrict__ k16,
    const f16* __restrict__ vt, const float* __restrict__ mask,
    const unsigned int* __restrict__ kn, const float* __restrict__ mm,
    float* __restrict__ out)
{
    __shared__ f16 Ks[2][64 * 64];
    __shared__ f16 Vs[2][64 * 64];
    __shared__ f16 Pt[4][64 * 16];   // per-wave [kv][q16], reused per rt pass

    const int tid = threadIdx.x;
    const int w = tid >> 6, lane = tid & 63;
    const int quad = lane >> 4, mh = lane & 15;
    const int bh = blockIdx.x, bbb = bh >> 4, h = bh & 15;
    const int q0 = blockIdx.y * 128;
    const float* maskb = mask + bbb * kS;

    int mS[2], cS[2];
#pragma unroll
    for (int i = 0; i < 2; ++i) {
        int P = (w * 2 + i) * 64 + lane;
        mS[i] = P >> 3;
        cS[i] = (P & 7) ^ (mS[i] & 7);
    }
    const f16* kp[2]; const f16* vp[2];
#pragma unroll
    for (int i = 0; i < 2; ++i) {
        kp[i] = k16 + ((size_t)bh * kS + mS[i]) * kHD + cS[i] * 8;
        vp[i] = vt  + ((size_t)bh * kHD + mS[i]) * kS + cS[i] * 8;
    }

    auto issue = [&](f16* Kb, f16* Vb) {
#pragma unroll
        for (int i = 0; i < 2; ++i) {
            async16(kp[i], Kb + (w * 2 + i) * 512);
            async16(vp[i], Vb + (w * 2 + i) * 512);
            kp[i] += 64 * kHD;
            vp[i] += 64;
        }
    };

    issue(Ks[0], Vs[0]);

    f16* PtW = &Pt[w][0];
    // AS3 address for tr-reads: group g reads rows g*8+{0..3} of the
    // [64][16] f16 row-major tile (lane addr = base + quad*256B + mh*8B;
    // +128B imm = +4 rows, +1024B imm = +32 rows for the ks=1 slice).
    const __attribute__((address_space(3))) f16* ptr_tr =
        (const __attribute__((address_space(3))) f16*)PtW + quad * 128 + mh * 4;

    f16x8 qf[2][2];
#pragma unroll
    for (int rt = 0; rt < 2; ++rt) {
        const f16* qrow = q16 + ((size_t)bh * kS + q0 + w * 32 + rt * 16 + mh) * kHD;
#pragma unroll
        for (int ks = 0; ks < 2; ++ks) {
            qf[rt][ks] = *(const f16x8*)(qrow + ks * 32 + quad * 8);
#pragma unroll
            for (int j = 0; j < 8; ++j) qf[rt][ks][j] *= (f16)0.125f;
        }
    }

    const float kn2 = __uint_as_float(kn[bh]);
    const float mmb = mm[bbb];
    float bndr[2][4];   // pre-scaled: -log2e * (bound)
#pragma unroll
    for (int rt = 0; rt < 2; ++rt) {
        float qn2 = 0.f;
#pragma unroll
        for (int ks = 0; ks < 2; ++ks)
#pragma unroll
            for (int j = 0; j < 8; ++j) {
                float v = (float)qf[rt][ks][j];
                qn2 += v * v;
            }
        qn2 += __shfl_xor(qn2, 16, 64);
        qn2 += __shfl_xor(qn2, 32, 64);
        const float bnd = sqrtf(qn2 * kn2) + mmb - 9.5f;
#pragma unroll
        for (int r = 0; r < 4; ++r)
            bndr[rt][r] = -kLog2e * __shfl(bnd, quad * 4 + r, 64);
    }

    // O is TRANSPOSED: O[rt][dt] holds d rows (quad*4+r), q col (rt*16+mh).
    // Od[rt] = ones^T * P accumulator: every row = denominator for q=mh.
    f32x4 O[2][4];
#pragma unroll
    for (int rt = 0; rt < 2; ++rt)
#pragma unroll
        for (int i = 0; i < 4; ++i) O[rt][i] = (f32x4){0.f, 0.f, 0.f, 0.f};
    f32x4 Od[2];
    Od[0] = (f32x4){0.f, 0.f, 0.f, 0.f};
    Od[1] = (f32x4){0.f, 0.f, 0.f, 0.f};
    const f16x8 onesv = {(f16)1.f, (f16)1.f, (f16)1.f, (f16)1.f,
                         (f16)1.f, (f16)1.f, (f16)1.f, (f16)1.f};

    auto step = [&](const f16* Kb, const f16* Vb, int jt) {
        uint2 pk1[4];   // rt1's packed P, parked until rt0's tr-read drains
        // ---- QK for BOTH rt per nt: kf loaded once (was twice) ----
#pragma unroll
        for (int nt = 0; nt < 4; ++nt) {
            f16x8 kf0 = *(const f16x8*)(Kb + phys8(nt * 16 + mh, 0 + quad) * 8);
            f16x8 kf1 = *(const f16x8*)(Kb + phys8(nt * 16 + mh, 4 + quad) * 8);
            f32x4 S0 = __builtin_amdgcn_mfma_f32_16x16x32_f16(
                qf[0][0], kf0, (f32x4){0.f, 0.f, 0.f, 0.f}, 0, 0, 0);
            S0 = __builtin_amdgcn_mfma_f32_16x16x32_f16(
                qf[0][1], kf1, S0, 0, 0, 0);
            f32x4 S1 = __builtin_amdgcn_mfma_f32_16x16x32_f16(
                qf[1][0], kf0, (f32x4){0.f, 0.f, 0.f, 0.f}, 0, 0, 0);
            S1 = __builtin_amdgcn_mfma_f32_16x16x32_f16(
                qf[1][1], kf1, S1, 0, 0, 0);
            const float mvl2 = kLog2e * maskb[jt + nt * 16 + mh];
            union { f16 h4[4]; uint2 u; } pk;
#pragma unroll
            for (int r = 0; r < 4; ++r)
                pk.h4[r] = (f16)fast_exp2(
                    fmaf(S0[r], kLog2e, mvl2) + bndr[0][r]);
            *(uint2*)(PtW + (nt * 16 + mh) * 16 + quad * 4) = pk.u;
#pragma unroll
            for (int r = 0; r < 4; ++r)
                pk.h4[r] = (f16)fast_exp2(
                    fmaf(S1[r], kLog2e, mvl2) + bndr[1][r]);
            pk1[nt] = pk.u;
        }
        // ---- rt0: transpose-read P (drains the rt0 Pt writes) ----
        f16x4 t0, t1, t2, t3;
        asm volatile(
            "s_waitcnt lgkmcnt(0)\n\t"
            "ds_read_b64_tr_b16 %0, %4\n\t"
            "ds_read_b64_tr_b16 %1, %4 offset:128\n\t"
            "ds_read_b64_tr_b16 %2, %4 offset:1024\n\t"
            "ds_read_b64_tr_b16 %3, %4 offset:1152\n\t"
            "s_waitcnt lgkmcnt(0)"
            : "=&v"(t0), "=&v"(t1), "=&v"(t2), "=&v"(t3)
            : "v"(ptr_tr) : "memory");
        __builtin_amdgcn_sched_barrier(0);
        f16x8 p0 = __builtin_shufflevector(t0, t1, 0, 1, 2, 3, 4, 5, 6, 7);
        f16x8 p1 = __builtin_shufflevector(t2, t3, 0, 1, 2, 3, 4, 5, 6, 7);
        // ---- rt1's Pt writes: overlap rt0's register-only PV MFMAs ----
#pragma unroll
        for (int nt = 0; nt < 4; ++nt)
            *(uint2*)(PtW + (nt * 16 + mh) * 16 + quad * 4) = pk1[nt];
        // ---- rt0 PV + denominator on the matrix pipe ----
        __builtin_amdgcn_s_setprio(1);
        Od[0] = __builtin_amdgcn_mfma_f32_16x16x32_f16(onesv, p0, Od[0], 0, 0, 0);
        Od[0] = __builtin_amdgcn_mfma_f32_16x16x32_f16(onesv, p1, Od[0], 0, 0, 0);
#pragma unroll
        for (int dt = 0; dt < 4; ++dt) {
            f16x8 vf0 = *(const f16x8*)(Vb + phys8(dt * 16 + mh, 0 + quad) * 8);
            f16x8 vf1 = *(const f16x8*)(Vb + phys8(dt * 16 + mh, 4 + quad) * 8);
            O[0][dt] = __builtin_amdgcn_mfma_f32_16x16x32_f16(
                vf0, p0, O[0][dt], 0, 0, 0);
            O[0][dt] = __builtin_amdgcn_mfma_f32_16x16x32_f16(
                vf1, p1, O[0][dt], 0, 0, 0);
        }
        __builtin_amdgcn_s_setprio(0);
        // ---- rt1: transpose-read (leading lgkmcnt drains rt1 writes) ----
        asm volatile(
            "s_waitcnt lgkmcnt(0)\n\t"
            "ds_read_b64_tr_b16 %0, %4\n\t"
            "ds_read_b64_tr_b16 %1, %4 offset:128\n\t"
            "ds_read_b64_tr_b16 %2, %4 offset:1024\n\t"
            "ds_read_b64_tr_b16 %3, %4 offset:1152\n\t"
            "s_waitcnt lgkmcnt(0)"
            : "=&v"(t0), "=&v"(t1), "=&v"(t2), "=&v"(t3)
            : "v"(ptr_tr) : "memory");
        __builtin_amdgcn_sched_barrier(0);
        p0 = __builtin_shufflevector(t0, t1, 0, 1, 2, 3, 4, 5, 6, 7);
        p1 = __builtin_shufflevector(t2, t3, 0, 1, 2, 3, 4, 5, 6, 7);
        // ---- rt1 PV + denominator ----
        __builtin_amdgcn_s_setprio(1);
        Od[1] = __builtin_amdgcn_mfma_f32_16x16x32_f16(onesv, p0, Od[1], 0, 0, 0);
        Od[1] = __builtin_amdgcn_mfma_f32_16x16x32_f16(onesv, p1, Od[1], 0, 0, 0);
#pragma unroll
        for (int dt = 0; dt < 4; ++dt) {
            f16x8 vf0 = *(const f16x8*)(Vb + phys8(dt * 16 + mh, 0 + quad) * 8);
            f16x8 vf1 = *(const f16x8*)(Vb + phys8(dt * 16 + mh, 4 + quad) * 8);
            O[1][dt] = __builtin_amdgcn_mfma_f32_16x16x32_f16(
                vf0, p0, O[1][dt], 0, 0, 0);
            O[1][dt] = __builtin_amdgcn_mfma_f32_16x16x32_f16(
                vf1, p1, O[1][dt], 0, 0, 0);
        }
        __builtin_amdgcn_s_setprio(0);
    };

    __syncthreads();

    for (int jt = 0; jt < kS; jt += 128) {
        issue(Ks[1], Vs[1]);
        step(Ks[0], Vs[0], jt);
        __syncthreads();
        if (jt + 128 < kS) issue(Ks[0], Vs[0]);
        step(Ks[1], Vs[1], jt + 64);
        __syncthreads();
    }

#pragma unroll
    for (int rt = 0; rt < 2; ++rt) {
        const float inv = 1.0f / Od[rt][0];   // all 4 rows identical
        const int s = q0 + w * 32 + rt * 16 + mh;
        float* orow = out + ((size_t)(bbb * kS + s)) * kH + (h << 6);
#pragma unroll
        for (int dt = 0; dt < 4; ++dt) {
            f32x4 v;
            v[0] = O[rt][dt][0] * inv;
            v[1] = O[rt][dt][1] * inv;
            v[2] = O[rt][dt][2] * inv;
            v[3] = O[rt][dt][3] * inv;
            __builtin_nontemporal_store(v, (f32x4*)(orow + dt * 16 + quad * 4));
        }
    }
}

// ---------------------------------------------------------------------------
extern "C" void kernel_launch(void* const* d_in, const int* in_sizes, int n_in,
                              void* d_out, int out_size, void* d_ws, size_t ws_size,
                              hipStream_t stream) {
    (void)in_sizes; (void)n_in; (void)out_size; (void)ws_size;

    const float* hs   = (const float*)d_in[0];
    const float* mask = (const float*)d_in[1];
    const float* ce   = (const float*)d_in[2];
    const float* Wq   = (const float*)d_in[3];
    const float* bq   = (const float*)d_in[4];
    const float* Wk   = (const float*)d_in[5];
    const float* bk   = (const float*)d_in[6];
    const float* Wv   = (const float*)d_in[7];
    const float* bv   = (const float*)d_in[8];
    const float* Wcq  = (const float*)d_in[9];
    const float* bcq  = (const float*)d_in[10];
    const float* Wck  = (const float*)d_in[11];
    const float* bck  = (const float*)d_in[12];
    const float* wlqc = (const float*)d_in[13];
    const float* wlqq = (const float*)d_in[14];
    const float* wlkc = (const float*)d_in[15];
    const float* wlkk = (const float*)d_in[16];
    float* out = (float*)d_out;

    f16* hs16 = (f16*)d_ws;                            // 16.78 MB
    f16* Wt   = hs16 + (size_t)kB * kS * kH;           // 6.29 MB
    f16* q16  = Wt + (size_t)3 * kH * kH;              // 16.78 MB
    f16* k16  = q16 + (size_t)kRows * kHD;             // 16.78 MB
    f16* vt   = k16 + (size_t)kRows * kHD;             // 16.78 MB  [bh][d][s]
    f16* ce16 = vt + (size_t)kRows * kHD;              // 16.78 MB  [bh][s][d]
    f16* Wct  = ce16 + (size_t)kRows * kHD;            // 16 KB
    unsigned int* kn = (unsigned int*)(Wct + 2 * kHD * kHD);  // 128 u32
    float* mm = (float*)(kn + kBH);                    // 8 f32

    prep_all_kernel<<<dim3(8970), 256, 0, stream>>>(
        hs, ce, Wq, Wk, Wv, Wcq, Wck, mask,
        hs16, ce16, Wt, Wct, kn, mm);

    qkv_gemm_f16<<<dim3(kB * kS / 128, kH / 128, 3), 256, 0, stream>>>(
        hs16, Wt, bq, bk, bv, q16, k16, vt,
        ce16, Wct, bcq, bck, wlqc, wlqq, wlkc, wlkk, kn);

    attn_f16<<<dim3(kBH, kS / 128), 256, 0, stream>>>(
        q16, k16, vt, mask, kn, mm, out);
}

// Round 13
// 269.645 us; speedup vs baseline: 1.0046x; 1.0046x over previous
//
#include <hip/hip_runtime.h>

typedef _Float16 f16;
typedef f16   f16x8 __attribute__((ext_vector_type(8)));
typedef f16   f16x4 __attribute__((ext_vector_type(4)));
typedef float f32x4 __attribute__((ext_vector_type(4)));

namespace {
constexpr int kB  = 8;
constexpr int kS  = 1024;
constexpr int kH  = 1024;
constexpr int kNH = 16;
constexpr int kHD = 64;
constexpr int kBH = kB * kNH;            // 128
constexpr int kRows = kBH * kS;          // 131072
constexpr float kLog2e = 1.44269504088896f;
}

// Raw hardware 2^x (v_exp_f32).  Round-9 lesson: plain exp2f lowers to the
// OCML precise version (denormal fixup, ~8 ops + branch) without fast-math;
// __expf is the native 2-op path.
__device__ __forceinline__ float fast_exp2(float x) {
#if __has_builtin(__builtin_amdgcn_exp2f)
    return __builtin_amdgcn_exp2f(x);
#else
    return __expf(x * 0.693147180559945f);   // exp(x*ln2) == 2^x, native path
#endif
}

// async global->LDS, 16B per lane; LDS dest = wave-uniform base + lane*16.
// NOTE: only offset=0 is used — the offset immediate's LDS-vs-global
// semantics are unverified on gfx950 (round-4 NaN post-mortem).
__device__ __forceinline__ void async16(const f16* g, f16* l) {
    __builtin_amdgcn_global_load_lds(
        (const __attribute__((address_space(1))) unsigned int*)g,
        (__attribute__((address_space(3))) unsigned int*)l, 16, 0, 0);
}

// --- LDS chunk swizzles (16B chunks). Uniform bank-slot histogram per quad
// for MFMA fragment reads; invertible for global_load_lds staging. ---
__device__ __forceinline__ int phys4(int m, int c) {
    return ((m >> 1) << 3) | ((((m & 1) << 2) | c) ^ ((m >> 1) & 7));
}
__device__ __forceinline__ int phys8(int m, int c) {
    return (m << 3) | (c ^ (m & 7));
}

// ---------------------------------------------------------------------------
// ALL preprocessing in ONE launch (round 13).
//   blocks [0,8192):    cast hs (y=0) / ce (y=1) fp32 -> f16
//   blocks [8192,8960): transpose Wq/Wk/Wv fp32 [K][N] -> f16 [N][K]
//   blocks [8960,8970): Wcq/Wck transpose-cast + kn zero + mask max
// ---------------------------------------------------------------------------
__global__ __launch_bounds__(256) void prep_all_kernel(
    const float* __restrict__ hs, const float* __restrict__ ce,
    const float* __restrict__ Wq, const float* __restrict__ Wk,
    const float* __restrict__ Wv, const float* __restrict__ Wcq,
    const float* __restrict__ Wck, const float* __restrict__ mask,
    f16* __restrict__ hs16, f16* __restrict__ ce16, f16* __restrict__ Wt,
    f16* __restrict__ Wct, unsigned int* __restrict__ kn,
    float* __restrict__ mm)
{
    const int id = blockIdx.x;
    const int t = threadIdx.x;
    __shared__ f16 T[64][72];
    __shared__ float red[4];

    if (id < 8192) {
        // ---- input casts: y=0 hs flat; y=1 ce head-split ----
        const int x = id & 4095, y = id >> 12;
        int i = (x * 256 + t) * 8;
        const float* src = y ? ce : hs;
        float4 a = *(const float4*)(src + i);
        float4 b = *(const float4*)(src + i + 4);
        union { f16 h[8]; uint4 u; } pk;
        pk.h[0] = (f16)a.x; pk.h[1] = (f16)a.y; pk.h[2] = (f16)a.z; pk.h[3] = (f16)a.w;
        pk.h[4] = (f16)b.x; pk.h[5] = (f16)b.y; pk.h[6] = (f16)b.z; pk.h[7] = (f16)b.w;
        if (y == 0) {
            *(uint4*)(hs16 + i) = pk.u;
        } else {
            int row = i >> 10, col = i & 1023;
            int bb = row >> 10, s = row & 1023;
            int h = col >> 6, d = col & 63;
            size_t o = ((((size_t)(bb * kNH + h) << 10) | s) << 6) | d;
            *(uint4*)(ce16 + o) = pk.u;
        }
    } else if (id < 8960) {
        // ---- W transpose+cast ----
        const int tt = id - 8192;
        const int bx = tt & 15, by = (tt >> 4) & 15, bz = tt >> 8;
        const float* W = (bz == 0) ? Wq : (bz == 1) ? Wk : Wv;
        f16* out = Wt + (size_t)bz * kH * kH;
        const int k0 = by * 64, n0 = bx * 64;
#pragma unroll
        for (int i = 0; i < 4; ++i) {
            int idx = t + i * 256;
            int r = idx >> 4, cb = (idx & 15) * 4;
            float4 v = *(const float4*)(W + (size_t)(k0 + r) * kH + n0 + cb);
            T[cb + 0][r] = (f16)v.x; T[cb + 1][r] = (f16)v.y;
            T[cb + 2][r] = (f16)v.z; T[cb + 3][r] = (f16)v.w;
        }
        __syncthreads();
#pragma unroll
        for (int i = 0; i < 4; ++i) {
            int idx = t + i * 256;
            int r = idx >> 4, cb = (idx & 15) * 4;
            union { f16 h[4]; uint2 u; } pk;
#pragma unroll
            for (int j = 0; j < 4; ++j) pk.h[j] = T[r][cb + j];
            *(uint2*)(out + (size_t)(n0 + r) * kH + k0 + cb) = pk.u;
        }
    } else {
        // ---- small prep ----
        const int bx = id - 8960;
        if (bx < 2) {
            const float* W = bx ? Wck : Wcq;
            f16* out = Wct + bx * kHD * kHD;
#pragma unroll
            for (int i = 0; i < 16; ++i) {
                int idx = i * 256 + t;
                int k = idx >> 6, n = idx & 63;
                out[n * 64 + k] = (f16)W[idx];
            }
            if (bx == 0 && t < kBH) kn[t] = 0u;
        } else {
            const int b = bx - 2;
            const float* mp = mask + b * kS;
            float v = fmaxf(fmaxf(mp[t], mp[t + 256]), fmaxf(mp[t + 512], mp[t + 768]));
#pragma unroll
            for (int off = 1; off < 64; off <<= 1) v = fmaxf(v, __shfl_xor(v, off, 64));
            if ((t & 63) == 0) red[t >> 6] = v;
            __syncthreads();
            if (t == 0) mm[b] = fmaxf(fmaxf(red[0], red[1]), fmaxf(red[2], red[3]));
        }
    }
}

// ---------------------------------------------------------------------------
// QKV GEMM + FUSED CONTEXT GATING (round 16) with the round-17 XB
// XOR-swizzle (conflict-free epilogue: SQ_LDS_BANK_CONFLICT 524K -> 0,
// verified round 12).  K-loop: round-11 diet, no spill, 3 waves/SIMD.
// ---------------------------------------------------------------------------
__global__ __launch_bounds__(256, 3) void qkv_gemm_f16(
    const f16* __restrict__ hs16, const f16* __restrict__ Wt,
    const float* __restrict__ bq, const float* __restrict__ bk,
    const float* __restrict__ bv,
    f16* __restrict__ q16, f16* __restrict__ k16, f16* __restrict__ vt,
    const f16* __restrict__ ce16, const f16* __restrict__ Wct,
    const float* __restrict__ bcq, const float* __restrict__ bck,
    const float* __restrict__ wlqc, const float* __restrict__ wlqq,
    const float* __restrict__ wlkc, const float* __restrict__ wlkk,
    unsigned int* __restrict__ kn)
{
    const int z = blockIdx.z;
    const f16* Bmat = Wt + (size_t)z * kH * kH;
    const float* bias = (z == 0) ? bq : (z == 1) ? bk : bv;

    __shared__ f16 AB[2][2][128 * 32];   // [buf][A=0/B=1]

    const int tid = threadIdx.x;
    const int w = tid >> 6, lane = tid & 63;
    const int quad = lane >> 4, mh = lane & 15;
    const int wm = w >> 1, wn = w & 1;
    const int m0 = blockIdx.x * 128, n0 = blockIdx.y * 128;

    // A staging pointers (per-lane); B address = A address + block-uniform delta
    const f16* aptr[2];
#pragma unroll
    for (int i = 0; i < 2; ++i) {
        int P = (w * 2 + i) * 64 + lane;
        int r2 = P >> 3, s = P & 7;
        int bb = s ^ (r2 & 7);
        int m = (r2 << 1) | (bb >> 2), c = bb & 3;
        aptr[i] = hs16 + (size_t)(m0 + m) * kH + c * 8;
    }
    const ptrdiff_t bdelta = (Bmat + (size_t)n0 * kH) - (hs16 + (size_t)m0 * kH);

    auto issue = [&](int buf) {
#pragma unroll
        for (int i = 0; i < 2; ++i) {
            async16(aptr[i], AB[buf][0] + (w * 2 + i) * 512);
            async16(aptr[i] + bdelta, AB[buf][1] + (w * 2 + i) * 512);
            aptr[i] += 32;
        }
    };

    f32x4 acc[4][4];
#pragma unroll
    for (int i = 0; i < 4; ++i)
#pragma unroll
        for (int j = 0; j < 4; ++j) acc[i][j] = (f32x4){0.f, 0.f, 0.f, 0.f};

    // fragment base offsets; tile t adds +512 elements (phys4 linearity)
    const int aoff0 = phys4(wm * 64 + mh, quad) * 8;
    const int boff0 = phys4(wn * 64 + mh, quad) * 8;

    auto compute = [&](int buf) {
        f16x8 af[4], bf[4];
#pragma unroll
        for (int t = 0; t < 4; ++t)
            af[t] = *(const f16x8*)(AB[buf][0] + aoff0 + t * 512);
#pragma unroll
        for (int t = 0; t < 4; ++t)
            bf[t] = *(const f16x8*)(AB[buf][1] + boff0 + t * 512);
#pragma unroll
        for (int i = 0; i < 4; ++i)
#pragma unroll
            for (int j = 0; j < 4; ++j)
                acc[i][j] = __builtin_amdgcn_mfma_f32_16x16x32_f16(
                    af[i], bf[j], acc[i][j], 0, 0, 0);
    };

    issue(0);                 // tile 0
    __syncthreads();

    for (int it = 0; it < 16; ++it) {
        issue(1);             // prefetch tile 2it+1 (overlaps compute)
        compute(0);           // tile 2it
        __syncthreads();      // drain prefetch; buf0 free
        if (it < 15) issue(0);  // prefetch tile 2it+2
        compute(1);           // tile 2it+1
        __syncthreads();
    }

    if (z < 2) {
        // ---- fused gate epilogue (all same-wave; AB is dead -> XB alias) ----
        f16* outp = (z == 0) ? q16 : k16;
        const float* bc   = (z == 0) ? bcq  : bck;
        const float* wlc  = (z == 0) ? wlqc : wlkc;
        const float* wlxp = (z == 0) ? wlqq : wlkk;
        const int h   = (n0 + wn * 64) >> 6;
        const int bbb = m0 >> 10;
        const int sb  = (m0 & 1023) + wm * 64;
        const size_t rowbase = (size_t)(bbb * kNH + h) * kS + sb;
        f16* base = outp + rowbase * kHD;
        const f16* ceb = ce16 + rowbase * kHD;
        const f16* Wcg = Wct + (size_t)z * kHD * kHD;

        float bnv[4], bcv[4], wlcv[4], wlxv[4];
#pragma unroll
        for (int nt = 0; nt < 4; ++nt) {
            bnv[nt]  = bias[n0 + wn * 64 + nt * 16 + mh];
            const int d = nt * 16 + mh;
            bcv[nt]  = bc[d];
            wlcv[nt] = wlc[d];
            wlxv[nt] = wlxp[d];
        }
        // B fragments for the ce GEMM (L2-hot 16 KB table; round-14 pattern)
        f16x8 bfr[4][2];
#pragma unroll
        for (int nt = 0; nt < 4; ++nt)
#pragma unroll
            for (int ks = 0; ks < 2; ++ks)
                bfr[nt][ks] = *(const f16x8*)(
                    Wcg + (nt * 16 + mh) * 64 + (ks * 4 + quad) * 8);

        f16* XB = &AB[0][0][0] + w * 4096;   // per-wave 64x64 gated tile

#pragma unroll
        for (int mt = 0; mt < 4; ++mt) {
            const f16* cerow = ceb + (size_t)(mt * 16 + mh) * kHD;
            f16x8 a0 = *(const f16x8*)(cerow + quad * 8);
            f16x8 a1 = *(const f16x8*)(cerow + 32 + quad * 8);
            f32x4 accce[4];
#pragma unroll
            for (int nt = 0; nt < 4; ++nt) {
                accce[nt] = __builtin_amdgcn_mfma_f32_16x16x32_f16(
                    a0, bfr[nt][0], (f32x4){0.f, 0.f, 0.f, 0.f}, 0, 0, 0);
                accce[nt] = __builtin_amdgcn_mfma_f32_16x16x32_f16(
                    a1, bfr[nt][1], accce[nt], 0, 0, 0);
            }
#pragma unroll
            for (int r = 0; r < 4; ++r) {
                f16 x16[4], cq16[4];
                float t = 0.f;
#pragma unroll
                for (int nt = 0; nt < 4; ++nt) {
                    x16[nt] = (f16)(acc[mt][nt][r] + bnv[nt]);
                    const float vq = accce[nt][r] + bcv[nt];
                    cq16[nt] = (f16)vq;
                    t += (float)x16[nt] * wlxv[nt] + vq * wlcv[nt];
                }
                t += __shfl_xor(t, 1, 64);
                t += __shfl_xor(t, 2, 64);
                t += __shfl_xor(t, 4, 64);
                t += __shfl_xor(t, 8, 64);
                const float lam = 1.0f / (1.0f + __expf(-t));
                const int row = mt * 16 + quad * 4 + r;
#pragma unroll
                for (int nt = 0; nt < 4; ++nt) {
                    const int blk = (nt * 2 + (mh >> 3)) ^ (row & 7);
                    XB[row * 64 + (blk << 3) + (mh & 7)] =
                        (f16)((1.0f - lam) * (float)x16[nt] +
                              lam * (float)cq16[nt]);
                }
            }
        }
        // coalesced store (+ z==1: per-row |k|^2 max -> kn[bh])
        float wmax = 0.f;
#pragma unroll
        for (int p = 0; p < 8; ++p) {
            const int row = (lane >> 3) + p * 8;
            const int blk = (lane & 7) ^ (row & 7);
            union { uint4 u; f16 hh[8]; } v;
            v.u = *(const uint4*)(XB + row * 64 + (blk << 3));
            *(uint4*)(base + (size_t)row * kHD + (lane & 7) * 8) = v.u;
            if (z == 1) {
                float ss = 0.f;
#pragma unroll
                for (int j = 0; j < 8; ++j) {
                    const float f = (float)v.hh[j];
                    ss += f * f;
                }
                ss += __shfl_xor(ss, 1, 64);
                ss += __shfl_xor(ss, 2, 64);
                ss += __shfl_xor(ss, 4, 64);
                wmax = fmaxf(wmax, ss);
            }
        }
        if (z == 1) {
            wmax = fmaxf(wmax, __shfl_xor(wmax, 8, 64));
            wmax = fmaxf(wmax, __shfl_xor(wmax, 16, 64));
            wmax = fmaxf(wmax, __shfl_xor(wmax, 32, 64));
            if (lane == 0) atomicMax(&kn[bbb * kNH + h], __float_as_uint(wmax));
        }
    } else {
#pragma unroll
        for (int nt = 0; nt < 4; ++nt) {
            const int n = n0 + wn * 64 + nt * 16 + mh;
            const int h = n >> 6, d = n & 63;
            const float bn = bias[n];
#pragma unroll
            for (int mt = 0; mt < 4; ++mt) {
                int mbase = m0 + wm * 64 + mt * 16 + quad * 4;
                int bbb = mbase >> 10, s0 = mbase & 1023;
                union { f16 h4[4]; uint2 u; } pk;
#pragma unroll
                for (int r = 0; r < 4; ++r) pk.h4[r] = (f16)(acc[mt][nt][r] + bn);
                *(uint2*)(vt + ((size_t)(bbb * kNH + h) * kHD + d) * kS + s0) = pk.u;
            }
        }
    }
}

// ---------------------------------------------------------------------------
// MFMA flash attention — ROUND-11 VERSION (best measured: part of the
// 269.2 µs total).  Round-12's kf-once/parked-P restructure measured
// neutral-to-negative (rt1 chain already hidden by 4-wave TLP) — reverted.
// exp2-domain via raw v_exp_f32; denominator on matrix pipe.
// ---------------------------------------------------------------------------
__global__ __launch_bounds__(256, 4) void attn_f16(
    const f16* __restrict__ q16, const f16* __restrict__ k16,
    const f16* __restrict__ vt, const float* __restrict__ mask,
    const unsigned int* __restrict__ kn, const float* __restrict__ mm,
    float* __restrict__ out)
{
    __shared__ f16 Ks[2][64 * 64];
    __shared__ f16 Vs[2][64 * 64];
    __shared__ f16 Pt[4][64 * 16];   // per-wave [kv][q16], reused per rt pass

    const int tid = threadIdx.x;
    const int w = tid >> 6, lane = tid & 63;
    const int quad = lane >> 4, mh = lane & 15;
    const int bh = blockIdx.x, bbb = bh >> 4, h = bh & 15;
    const int q0 = blockIdx.y * 128;
    const float* maskb = mask + bbb * kS;

    int mS[2], cS[2];
#pragma unroll
    for (int i = 0; i < 2; ++i) {
        int P = (w * 2 + i) * 64 + lane;
        mS[i] = P >> 3;
        cS[i] = (P & 7) ^ (mS[i] & 7);
    }
    const f16* kp[2]; const f16* vp[2];
#pragma unroll
    for (int i = 0; i < 2; ++i) {
        kp[i] = k16 + ((size_t)bh * kS + mS[i]) * kHD + cS[i] * 8;
        vp[i] = vt  + ((size_t)bh * kHD + mS[i]) * kS + cS[i] * 8;
    }

    auto issue = [&](f16* Kb, f16* Vb) {
#pragma unroll
        for (int i = 0; i < 2; ++i) {
            async16(kp[i], Kb + (w * 2 + i) * 512);
            async16(vp[i], Vb + (w * 2 + i) * 512);
            kp[i] += 64 * kHD;
            vp[i] += 64;
        }
    };

    issue(Ks[0], Vs[0]);

    f16* PtW = &Pt[w][0];
    // AS3 address for tr-reads: group g reads rows g*8+{0..3} of the
    // [64][16] f16 row-major tile (lane addr = base + quad*256B + mh*8B;
    // +128B imm = +4 rows, +1024B imm = +32 rows for the ks=1 slice).
    const __attribute__((address_space(3))) f16* ptr_tr =
        (const __attribute__((address_space(3))) f16*)PtW + quad * 128 + mh * 4;

    f16x8 qf[2][2];
#pragma unroll
    for (int rt = 0; rt < 2; ++rt) {
        const f16* qrow = q16 + ((size_t)bh * kS + q0 + w * 32 + rt * 16 + mh) * kHD;
#pragma unroll
        for (int ks = 0; ks < 2; ++ks) {
            qf[rt][ks] = *(const f16x8*)(qrow + ks * 32 + quad * 8);
#pragma unroll
            for (int j = 0; j < 8; ++j) qf[rt][ks][j] *= (f16)0.125f;
        }
    }

    const float kn2 = __uint_as_float(kn[bh]);
    const float mmb = mm[bbb];
    float bndr[2][4];   // pre-scaled: -log2e * (bound)
#pragma unroll
    for (int rt = 0; rt < 2; ++rt) {
        float qn2 = 0.f;
#pragma unroll
        for (int ks = 0; ks < 2; ++ks)
#pragma unroll
            for (int j = 0; j < 8; ++j) {
                float v = (float)qf[rt][ks][j];
                qn2 += v * v;
            }
        qn2 += __shfl_xor(qn2, 16, 64);
        qn2 += __shfl_xor(qn2, 32, 64);
        const float bnd = sqrtf(qn2 * kn2) + mmb - 9.5f;
#pragma unroll
        for (int r = 0; r < 4; ++r)
            bndr[rt][r] = -kLog2e * __shfl(bnd, quad * 4 + r, 64);
    }

    // O is TRANSPOSED: O[rt][dt] holds d rows (quad*4+r), q col (rt*16+mh).
    // Od[rt] = ones^T * P accumulator: every row = denominator for q=mh.
    f32x4 O[2][4];
#pragma unroll
    for (int rt = 0; rt < 2; ++rt)
#pragma unroll
        for (int i = 0; i < 4; ++i) O[rt][i] = (f32x4){0.f, 0.f, 0.f, 0.f};
    f32x4 Od[2];
    Od[0] = (f32x4){0.f, 0.f, 0.f, 0.f};
    Od[1] = (f32x4){0.f, 0.f, 0.f, 0.f};
    const f16x8 onesv = {(f16)1.f, (f16)1.f, (f16)1.f, (f16)1.f,
                         (f16)1.f, (f16)1.f, (f16)1.f, (f16)1.f};

    auto step = [&](const f16* Kb, const f16* Vb, int jt) {
#pragma unroll
        for (int rt = 0; rt < 2; ++rt) {
            // ---- QK^T per nt: 2 MFMA -> raw exp2 -> packed P write
#pragma unroll
            for (int nt = 0; nt < 4; ++nt) {
                f16x8 kf0 = *(const f16x8*)(Kb + phys8(nt * 16 + mh, 0 + quad) * 8);
                f16x8 kf1 = *(const f16x8*)(Kb + phys8(nt * 16 + mh, 4 + quad) * 8);
                f32x4 S = __builtin_amdgcn_mfma_f32_16x16x32_f16(
                    qf[rt][0], kf0, (f32x4){0.f, 0.f, 0.f, 0.f}, 0, 0, 0);
                S = __builtin_amdgcn_mfma_f32_16x16x32_f16(
                    qf[rt][1], kf1, S, 0, 0, 0);
                const float mvl2 = kLog2e * maskb[jt + nt * 16 + mh];
                union { f16 h4[4]; uint2 u; } pk;
#pragma unroll
                for (int r = 0; r < 4; ++r)
                    pk.h4[r] = (f16)fast_exp2(
                        fmaf(S[r], kLog2e, mvl2) + bndr[rt][r]);
                *(uint2*)(PtW + (nt * 16 + mh) * 16 + quad * 4) = pk.u;
            }
            // ---- transpose-read P as PV B-operand: col=q(mh), k=kv contiguous
            f16x4 t0, t1, t2, t3;
            asm volatile(
                "s_waitcnt lgkmcnt(0)\n\t"
                "ds_read_b64_tr_b16 %0, %4\n\t"
                "ds_read_b64_tr_b16 %1, %4 offset:128\n\t"
                "ds_read_b64_tr_b16 %2, %4 offset:1024\n\t"
                "ds_read_b64_tr_b16 %3, %4 offset:1152\n\t"
                "s_waitcnt lgkmcnt(0)"
                : "=&v"(t0), "=&v"(t1), "=&v"(t2), "=&v"(t3)
                : "v"(ptr_tr) : "memory");
            __builtin_amdgcn_sched_barrier(0);
            f16x8 p0 = __builtin_shufflevector(t0, t1, 0, 1, 2, 3, 4, 5, 6, 7);
            f16x8 p1 = __builtin_shufflevector(t2, t3, 0, 1, 2, 3, 4, 5, 6, 7);
            // ---- PV + denominator, all on the matrix pipe
            __builtin_amdgcn_s_setprio(1);
            Od[rt] = __builtin_amdgcn_mfma_f32_16x16x32_f16(
                onesv, p0, Od[rt], 0, 0, 0);
            Od[rt] = __builtin_amdgcn_mfma_f32_16x16x32_f16(
                onesv, p1, Od[rt], 0, 0, 0);
#pragma unroll
            for (int dt = 0; dt < 4; ++dt) {
                f16x8 vf0 = *(const f16x8*)(Vb + phys8(dt * 16 + mh, 0 + quad) * 8);
                f16x8 vf1 = *(const f16x8*)(Vb + phys8(dt * 16 + mh, 4 + quad) * 8);
                O[rt][dt] = __builtin_amdgcn_mfma_f32_16x16x32_f16(
                    vf0, p0, O[rt][dt], 0, 0, 0);
                O[rt][dt] = __builtin_amdgcn_mfma_f32_16x16x32_f16(
                    vf1, p1, O[rt][dt], 0, 0, 0);
            }
            __builtin_amdgcn_s_setprio(0);
        }
    };

    __syncthreads();

    for (int jt = 0; jt < kS; jt += 128) {
        issue(Ks[1], Vs[1]);
        step(Ks[0], Vs[0], jt);
        __syncthreads();
        if (jt + 128 < kS) issue(Ks[0], Vs[0]);
        step(Ks[1], Vs[1], jt + 64);
        __syncthreads();
    }

#pragma unroll
    for (int rt = 0; rt < 2; ++rt) {
        const float inv = 1.0f / Od[rt][0];   // all 4 rows identical
        const int s = q0 + w * 32 + rt * 16 + mh;
        float* orow = out + ((size_t)(bbb * kS + s)) * kH + (h << 6);
#pragma unroll
        for (int dt = 0; dt < 4; ++dt) {
            f32x4 v;
            v[0] = O[rt][dt][0] * inv;
            v[1] = O[rt][dt][1] * inv;
            v[2] = O[rt][dt][2] * inv;
            v[3] = O[rt][dt][3] * inv;
            __builtin_nontemporal_store(v, (f32x4*)(orow + dt * 16 + quad * 4));
        }
    }
}

// ---------------------------------------------------------------------------
extern "C" void kernel_launch(void* const* d_in, const int* in_sizes, int n_in,
                              void* d_out, int out_size, void* d_ws, size_t ws_size,
                              hipStream_t stream) {
    (void)in_sizes; (void)n_in; (void)out_size; (void)ws_size;

    const float* hs   = (const float*)d_in[0];
    const float* mask = (const float*)d_in[1];
    const float* ce   = (const float*)d_in[2];
    const float* Wq   = (const float*)d_in[3];
    const float* bq   = (const float*)d_in[4];
    const float* Wk   = (const float*)d_in[5];
    const float* bk   = (const float*)d_in[6];
    const float* Wv   = (const float*)d_in[7];
    const float* bv   = (const float*)d_in[8];
    const float* Wcq  = (const float*)d_in[9];
    const float* bcq  = (const float*)d_in[10];
    const float* Wck  = (const float*)d_in[11];
    const float* bck  = (const float*)d_in[12];
    const float* wlqc = (const float*)d_in[13];
    const float* wlqq = (const float*)d_in[14];
    const float* wlkc = (const float*)d_in[15];
    const float* wlkk = (const float*)d_in[16];
    float* out = (float*)d_out;

    f16* hs16 = (f16*)d_ws;                            // 16.78 MB
    f16* Wt   = hs16 + (size_t)kB * kS * kH;           // 6.29 MB
    f16* q16  = Wt + (size_t)3 * kH * kH;              // 16.78 MB
    f16* k16  = q16 + (size_t)kRows * kHD;             // 16.78 MB
    f16* vt   = k16 + (size_t)kRows * kHD;             // 16.78 MB  [bh][d][s]
    f16* ce16 = vt + (size_t)kRows * kHD;              // 16.78 MB  [bh][s][d]
    f16* Wct  = ce16 + (size_t)kRows * kHD;            // 16 KB
    unsigned int* kn = (unsigned int*)(Wct + 2 * kHD * kHD);  // 128 u32
    float* mm = (float*)(kn + kBH);                    // 8 f32

    prep_all_kernel<<<dim3(8970), 256, 0, stream>>>(
        hs, ce, Wq, Wk, Wv, Wcq, Wck, mask,
        hs16, ce16, Wt, Wct, kn, mm);

    qkv_gemm_f16<<<dim3(kB * kS / 128, kH / 128, 3), 256, 0, stream>>>(
        hs16, Wt, bq, bk, bv, q16, k16, vt,
        ce16, Wct, bcq, bck, wlqc, wlqq, wlkc, wlkk, kn);

    attn_f16<<<dim3(kBH, kS / 128), 256, 0, stream>>>(
        q16, k16, vt, mask, kn, mm, out);
}

// Round 14
// 268.781 us; speedup vs baseline: 1.0078x; 1.0032x over previous
//
#include <hip/hip_runtime.h>

typedef _Float16 f16;
typedef f16   f16x8 __attribute__((ext_vector_type(8)));
typedef f16   f16x4 __attribute__((ext_vector_type(4)));
typedef float f32x4 __attribute__((ext_vector_type(4)));

namespace {
constexpr int kB  = 8;
constexpr int kS  = 1024;
constexpr int kH  = 1024;
constexpr int kNH = 16;
constexpr int kHD = 64;
constexpr int kBH = kB * kNH;            // 128
constexpr int kRows = kBH * kS;          // 131072
constexpr float kLog2e = 1.44269504088896f;
}

// Raw hardware 2^x (v_exp_f32).  Round-9 lesson: plain exp2f lowers to the
// OCML precise version (denormal fixup, ~8 ops + branch) without fast-math;
// __expf is the native 2-op path.
__device__ __forceinline__ float fast_exp2(float x) {
#if __has_builtin(__builtin_amdgcn_exp2f)
    return __builtin_amdgcn_exp2f(x);
#else
    return __expf(x * 0.693147180559945f);   // exp(x*ln2) == 2^x, native path
#endif
}

// async global->LDS, 16B per lane; LDS dest = wave-uniform base + lane*16.
// NOTE: only offset=0 is used — the offset immediate's LDS-vs-global
// semantics are unverified on gfx950 (round-4 NaN post-mortem).
__device__ __forceinline__ void async16(const f16* g, f16* l) {
    __builtin_amdgcn_global_load_lds(
        (const __attribute__((address_space(1))) unsigned int*)g,
        (__attribute__((address_space(3))) unsigned int*)l, 16, 0, 0);
}

// --- LDS chunk swizzles (16B chunks). Uniform bank-slot histogram per quad
// for MFMA fragment reads; invertible for global_load_lds staging. ---
__device__ __forceinline__ int phys4(int m, int c) {
    return ((m >> 1) << 3) | ((((m & 1) << 2) | c) ^ ((m >> 1) & 7));
}
__device__ __forceinline__ int phys8(int m, int c) {
    return (m << 3) | (c ^ (m & 7));
}

// ---------------------------------------------------------------------------
// Preprocessing, ONE launch.  Round 19: the ce cast plane is DELETED —
// ce16's only consumer was qkv's fused gate epilogue (since round 16),
// which now reads raw fp32 ce directly.  -48 MB of prep HBM traffic.
//   blocks [0,4096):    cast hs fp32 -> f16 flat
//   blocks [4096,4864): transpose Wq/Wk/Wv fp32 [K][N] -> f16 [N][K]
//   blocks [4864,4874): Wcq/Wck transpose-cast + kn zero + mask max
// ---------------------------------------------------------------------------
__global__ __launch_bounds__(256) void prep_all_kernel(
    const float* __restrict__ hs,
    const float* __restrict__ Wq, const float* __restrict__ Wk,
    const float* __restrict__ Wv, const float* __restrict__ Wcq,
    const float* __restrict__ Wck, const float* __restrict__ mask,
    f16* __restrict__ hs16, f16* __restrict__ Wt,
    f16* __restrict__ Wct, unsigned int* __restrict__ kn,
    float* __restrict__ mm)
{
    const int id = blockIdx.x;
    const int t = threadIdx.x;
    __shared__ f16 T[64][72];
    __shared__ float red[4];

    if (id < 4096) {
        // ---- hs cast, flat ----
        int i = (id * 256 + t) * 8;
        float4 a = *(const float4*)(hs + i);
        float4 b = *(const float4*)(hs + i + 4);
        union { f16 h[8]; uint4 u; } pk;
        pk.h[0] = (f16)a.x; pk.h[1] = (f16)a.y; pk.h[2] = (f16)a.z; pk.h[3] = (f16)a.w;
        pk.h[4] = (f16)b.x; pk.h[5] = (f16)b.y; pk.h[6] = (f16)b.z; pk.h[7] = (f16)b.w;
        *(uint4*)(hs16 + i) = pk.u;
    } else if (id < 4864) {
        // ---- W transpose+cast ----
        const int tt = id - 4096;
        const int bx = tt & 15, by = (tt >> 4) & 15, bz = tt >> 8;
        const float* W = (bz == 0) ? Wq : (bz == 1) ? Wk : Wv;
        f16* out = Wt + (size_t)bz * kH * kH;
        const int k0 = by * 64, n0 = bx * 64;
#pragma unroll
        for (int i = 0; i < 4; ++i) {
            int idx = t + i * 256;
            int r = idx >> 4, cb = (idx & 15) * 4;
            float4 v = *(const float4*)(W + (size_t)(k0 + r) * kH + n0 + cb);
            T[cb + 0][r] = (f16)v.x; T[cb + 1][r] = (f16)v.y;
            T[cb + 2][r] = (f16)v.z; T[cb + 3][r] = (f16)v.w;
        }
        __syncthreads();
#pragma unroll
        for (int i = 0; i < 4; ++i) {
            int idx = t + i * 256;
            int r = idx >> 4, cb = (idx & 15) * 4;
            union { f16 h[4]; uint2 u; } pk;
#pragma unroll
            for (int j = 0; j < 4; ++j) pk.h[j] = T[r][cb + j];
            *(uint2*)(out + (size_t)(n0 + r) * kH + k0 + cb) = pk.u;
        }
    } else {
        // ---- small prep ----
        const int bx = id - 4864;
        if (bx < 2) {
            const float* W = bx ? Wck : Wcq;
            f16* out = Wct + bx * kHD * kHD;
#pragma unroll
            for (int i = 0; i < 16; ++i) {
                int idx = i * 256 + t;
                int k = idx >> 6, n = idx & 63;
                out[n * 64 + k] = (f16)W[idx];
            }
            if (bx == 0 && t < kBH) kn[t] = 0u;
        } else {
            const int b = bx - 2;
            const float* mp = mask + b * kS;
            float v = fmaxf(fmaxf(mp[t], mp[t + 256]), fmaxf(mp[t + 512], mp[t + 768]));
#pragma unroll
            for (int off = 1; off < 64; off <<= 1) v = fmaxf(v, __shfl_xor(v, off, 64));
            if ((t & 63) == 0) red[t >> 6] = v;
            __syncthreads();
            if (t == 0) mm[b] = fmaxf(fmaxf(red[0], red[1]), fmaxf(red[2], red[3]));
        }
    }
}

// ---------------------------------------------------------------------------
// QKV GEMM + FUSED CONTEXT GATING.  Round 19: the gate epilogue reads raw
// fp32 ce (same address reorder + same (f16) rounding prep's cast applied,
// so A-fragments are bit-identical); ce16 intermediate deleted.
// K-loop: round-11 diet; XB epilogue: round-17 XOR swizzle (0 conflicts).
// ---------------------------------------------------------------------------
__global__ __launch_bounds__(256, 3) void qkv_gemm_f16(
    const f16* __restrict__ hs16, const f16* __restrict__ Wt,
    const float* __restrict__ bq, const float* __restrict__ bk,
    const float* __restrict__ bv,
    f16* __restrict__ q16, f16* __restrict__ k16, f16* __restrict__ vt,
    const float* __restrict__ ce, const f16* __restrict__ Wct,
    const float* __restrict__ bcq, const float* __restrict__ bck,
    const float* __restrict__ wlqc, const float* __restrict__ wlqq,
    const float* __restrict__ wlkc, const float* __restrict__ wlkk,
    unsigned int* __restrict__ kn)
{
    const int z = blockIdx.z;
    const f16* Bmat = Wt + (size_t)z * kH * kH;
    const float* bias = (z == 0) ? bq : (z == 1) ? bk : bv;

    __shared__ f16 AB[2][2][128 * 32];   // [buf][A=0/B=1]

    const int tid = threadIdx.x;
    const int w = tid >> 6, lane = tid & 63;
    const int quad = lane >> 4, mh = lane & 15;
    const int wm = w >> 1, wn = w & 1;
    const int m0 = blockIdx.x * 128, n0 = blockIdx.y * 128;

    // A staging pointers (per-lane); B address = A address + block-uniform delta
    const f16* aptr[2];
#pragma unroll
    for (int i = 0; i < 2; ++i) {
        int P = (w * 2 + i) * 64 + lane;
        int r2 = P >> 3, s = P & 7;
        int bb = s ^ (r2 & 7);
        int m = (r2 << 1) | (bb >> 2), c = bb & 3;
        aptr[i] = hs16 + (size_t)(m0 + m) * kH + c * 8;
    }
    const ptrdiff_t bdelta = (Bmat + (size_t)n0 * kH) - (hs16 + (size_t)m0 * kH);

    auto issue = [&](int buf) {
#pragma unroll
        for (int i = 0; i < 2; ++i) {
            async16(aptr[i], AB[buf][0] + (w * 2 + i) * 512);
            async16(aptr[i] + bdelta, AB[buf][1] + (w * 2 + i) * 512);
            aptr[i] += 32;
        }
    };

    f32x4 acc[4][4];
#pragma unroll
    for (int i = 0; i < 4; ++i)
#pragma unroll
        for (int j = 0; j < 4; ++j) acc[i][j] = (f32x4){0.f, 0.f, 0.f, 0.f};

    // fragment base offsets; tile t adds +512 elements (phys4 linearity)
    const int aoff0 = phys4(wm * 64 + mh, quad) * 8;
    const int boff0 = phys4(wn * 64 + mh, quad) * 8;

    auto compute = [&](int buf) {
        f16x8 af[4], bf[4];
#pragma unroll
        for (int t = 0; t < 4; ++t)
            af[t] = *(const f16x8*)(AB[buf][0] + aoff0 + t * 512);
#pragma unroll
        for (int t = 0; t < 4; ++t)
            bf[t] = *(const f16x8*)(AB[buf][1] + boff0 + t * 512);
#pragma unroll
        for (int i = 0; i < 4; ++i)
#pragma unroll
            for (int j = 0; j < 4; ++j)
                acc[i][j] = __builtin_amdgcn_mfma_f32_16x16x32_f16(
                    af[i], bf[j], acc[i][j], 0, 0, 0);
    };

    issue(0);                 // tile 0
    __syncthreads();

    for (int it = 0; it < 16; ++it) {
        issue(1);             // prefetch tile 2it+1 (overlaps compute)
        compute(0);           // tile 2it
        __syncthreads();      // drain prefetch; buf0 free
        if (it < 15) issue(0);  // prefetch tile 2it+2
        compute(1);           // tile 2it+1
        __syncthreads();
    }

    if (z < 2) {
        // ---- fused gate epilogue (all same-wave; AB is dead -> XB alias) ----
        f16* outp = (z == 0) ? q16 : k16;
        const float* bc   = (z == 0) ? bcq  : bck;
        const float* wlc  = (z == 0) ? wlqc : wlkc;
        const float* wlxp = (z == 0) ? wlqq : wlkk;
        const int h   = (n0 + wn * 64) >> 6;
        const int bbb = m0 >> 10;
        const int sb  = (m0 & 1023) + wm * 64;
        const size_t rowbase = (size_t)(bbb * kNH + h) * kS + sb;
        f16* base = outp + rowbase * kHD;
        // raw ce [B,S,H]: row (bbb, sb+r) at ce + (bbb*kS+sb+r)*kH + h*64
        const float* ceb = ce + ((size_t)(bbb * kS + sb)) * kH + (h << 6);
        const f16* Wcg = Wct + (size_t)z * kHD * kHD;

        float bnv[4], bcv[4], wlcv[4], wlxv[4];
#pragma unroll
        for (int nt = 0; nt < 4; ++nt) {
            bnv[nt]  = bias[n0 + wn * 64 + nt * 16 + mh];
            const int d = nt * 16 + mh;
            bcv[nt]  = bc[d];
            wlcv[nt] = wlc[d];
            wlxv[nt] = wlxp[d];
        }
        // B fragments for the ce GEMM (L2-hot 16 KB table; round-14 pattern)
        f16x8 bfr[4][2];
#pragma unroll
        for (int nt = 0; nt < 4; ++nt)
#pragma unroll
            for (int ks = 0; ks < 2; ++ks)
                bfr[nt][ks] = *(const f16x8*)(
                    Wcg + (nt * 16 + mh) * 64 + (ks * 4 + quad) * 8);

        f16* XB = &AB[0][0][0] + w * 4096;   // per-wave 64x64 gated tile

#pragma unroll
        for (int mt = 0; mt < 4; ++mt) {
            const float* crow = ceb + (size_t)(mt * 16 + mh) * kH;
            float4 c0 = *(const float4*)(crow + quad * 8);
            float4 c1 = *(const float4*)(crow + quad * 8 + 4);
            float4 c2 = *(const float4*)(crow + 32 + quad * 8);
            float4 c3 = *(const float4*)(crow + 32 + quad * 8 + 4);
            f16x8 a0 = {(f16)c0.x, (f16)c0.y, (f16)c0.z, (f16)c0.w,
                        (f16)c1.x, (f16)c1.y, (f16)c1.z, (f16)c1.w};
            f16x8 a1 = {(f16)c2.x, (f16)c2.y, (f16)c2.z, (f16)c2.w,
                        (f16)c3.x, (f16)c3.y, (f16)c3.z, (f16)c3.w};
            f32x4 accce[4];
#pragma unroll
            for (int nt = 0; nt < 4; ++nt) {
                accce[nt] = __builtin_amdgcn_mfma_f32_16x16x32_f16(
                    a0, bfr[nt][0], (f32x4){0.f, 0.f, 0.f, 0.f}, 0, 0, 0);
                accce[nt] = __builtin_amdgcn_mfma_f32_16x16x32_f16(
                    a1, bfr[nt][1], accce[nt], 0, 0, 0);
            }
#pragma unroll
            for (int r = 0; r < 4; ++r) {
                f16 x16[4], cq16[4];
                float t = 0.f;
#pragma unroll
                for (int nt = 0; nt < 4; ++nt) {
                    x16[nt] = (f16)(acc[mt][nt][r] + bnv[nt]);
                    const float vq = accce[nt][r] + bcv[nt];
                    cq16[nt] = (f16)vq;
                    t += (float)x16[nt] * wlxv[nt] + vq * wlcv[nt];
                }
                t += __shfl_xor(t, 1, 64);
                t += __shfl_xor(t, 2, 64);
                t += __shfl_xor(t, 4, 64);
                t += __shfl_xor(t, 8, 64);
                const float lam = 1.0f / (1.0f + __expf(-t));
                const int row = mt * 16 + quad * 4 + r;
#pragma unroll
                for (int nt = 0; nt < 4; ++nt) {
                    const int blk = (nt * 2 + (mh >> 3)) ^ (row & 7);
                    XB[row * 64 + (blk << 3) + (mh & 7)] =
                        (f16)((1.0f - lam) * (float)x16[nt] +
                              lam * (float)cq16[nt]);
                }
            }
        }
        // coalesced store (+ z==1: per-row |k|^2 max -> kn[bh])
        float wmax = 0.f;
#pragma unroll
        for (int p = 0; p < 8; ++p) {
            const int row = (lane >> 3) + p * 8;
            const int blk = (lane & 7) ^ (row & 7);
            union { uint4 u; f16 hh[8]; } v;
            v.u = *(const uint4*)(XB + row * 64 + (blk << 3));
            *(uint4*)(base + (size_t)row * kHD + (lane & 7) * 8) = v.u;
            if (z == 1) {
                float ss = 0.f;
#pragma unroll
                for (int j = 0; j < 8; ++j) {
                    const float f = (float)v.hh[j];
                    ss += f * f;
                }
                ss += __shfl_xor(ss, 1, 64);
                ss += __shfl_xor(ss, 2, 64);
                ss += __shfl_xor(ss, 4, 64);
                wmax = fmaxf(wmax, ss);
            }
        }
        if (z == 1) {
            wmax = fmaxf(wmax, __shfl_xor(wmax, 8, 64));
            wmax = fmaxf(wmax, __shfl_xor(wmax, 16, 64));
            wmax = fmaxf(wmax, __shfl_xor(wmax, 32, 64));
            if (lane == 0) atomicMax(&kn[bbb * kNH + h], __float_as_uint(wmax));
        }
    } else {
#pragma unroll
        for (int nt = 0; nt < 4; ++nt) {
            const int n = n0 + wn * 64 + nt * 16 + mh;
            const int h = n >> 6, d = n & 63;
            const float bn = bias[n];
#pragma unroll
            for (int mt = 0; mt < 4; ++mt) {
                int mbase = m0 + wm * 64 + mt * 16 + quad * 4;
                int bbb = mbase >> 10, s0 = mbase & 1023;
                union { f16 h4[4]; uint2 u; } pk;
#pragma unroll
                for (int r = 0; r < 4; ++r) pk.h4[r] = (f16)(acc[mt][nt][r] + bn);
                *(uint2*)(vt + ((size_t)(bbb * kNH + h) * kHD + d) * kS + s0) = pk.u;
            }
        }
    }
}

// ---------------------------------------------------------------------------
// MFMA flash attention (round-11 version, best measured; exp2-domain via
// raw v_exp_f32; denominator on matrix pipe; verified absmax 0.001953125).
// ---------------------------------------------------------------------------
__global__ __launch_bounds__(256, 4) void attn_f16(
    const f16* __restrict__ q16, const f16* __restrict__ k16,
    const f16* __restrict__ vt, const float* __restrict__ mask,
    const unsigned int* __restrict__ kn, const float* __restrict__ mm,
    float* __restrict__ out)
{
    __shared__ f16 Ks[2][64 * 64];
    __shared__ f16 Vs[2][64 * 64];
    __shared__ f16 Pt[4][64 * 16];   // per-wave [kv][q16], reused per rt pass

    const int tid = threadIdx.x;
    const int w = tid >> 6, lane = tid & 63;
    const int quad = lane >> 4, mh = lane & 15;
    const int bh = blockIdx.x, bbb = bh >> 4, h = bh & 15;
    const int q0 = blockIdx.y * 128;
    const float* maskb = mask + bbb * kS;

    int mS[2], cS[2];
#pragma unroll
    for (int i = 0; i < 2; ++i) {
        int P = (w * 2 + i) * 64 + lane;
        mS[i] = P >> 3;
        cS[i] = (P & 7) ^ (mS[i] & 7);
    }
    const f16* kp[2]; const f16* vp[2];
#pragma unroll
    for (int i = 0; i < 2; ++i) {
        kp[i] = k16 + ((size_t)bh * kS + mS[i]) * kHD + cS[i] * 8;
        vp[i] = vt  + ((size_t)bh * kHD + mS[i]) * kS + cS[i] * 8;
    }

    auto issue = [&](f16* Kb, f16* Vb) {
#pragma unroll
        for (int i = 0; i < 2; ++i) {
            async16(kp[i], Kb + (w * 2 + i) * 512);
            async16(vp[i], Vb + (w * 2 + i) * 512);
            kp[i] += 64 * kHD;
            vp[i] += 64;
        }
    };

    issue(Ks[0], Vs[0]);

    f16* PtW = &Pt[w][0];
    // AS3 address for tr-reads: group g reads rows g*8+{0..3} of the
    // [64][16] f16 row-major tile (lane addr = base + quad*256B + mh*8B;
    // +128B imm = +4 rows, +1024B imm = +32 rows for the ks=1 slice).
    const __attribute__((address_space(3))) f16* ptr_tr =
        (const __attribute__((address_space(3))) f16*)PtW + quad * 128 + mh * 4;

    f16x8 qf[2][2];
#pragma unroll
    for (int rt = 0; rt < 2; ++rt) {
        const f16* qrow = q16 + ((size_t)bh * kS + q0 + w * 32 + rt * 16 + mh) * kHD;
#pragma unroll
        for (int ks = 0; ks < 2; ++ks) {
            qf[rt][ks] = *(const f16x8*)(qrow + ks * 32 + quad * 8);
#pragma unroll
            for (int j = 0; j < 8; ++j) qf[rt][ks][j] *= (f16)0.125f;
        }
    }

    const float kn2 = __uint_as_float(kn[bh]);
    const float mmb = mm[bbb];
    float bndr[2][4];   // pre-scaled: -log2e * (bound)
#pragma unroll
    for (int rt = 0; rt < 2; ++rt) {
        float qn2 = 0.f;
#pragma unroll
        for (int ks = 0; ks < 2; ++ks)
#pragma unroll
            for (int j = 0; j < 8; ++j) {
                float v = (float)qf[rt][ks][j];
                qn2 += v * v;
            }
        qn2 += __shfl_xor(qn2, 16, 64);
        qn2 += __shfl_xor(qn2, 32, 64);
        const float bnd = sqrtf(qn2 * kn2) + mmb - 9.5f;
#pragma unroll
        for (int r = 0; r < 4; ++r)
            bndr[rt][r] = -kLog2e * __shfl(bnd, quad * 4 + r, 64);
    }

    // O is TRANSPOSED: O[rt][dt] holds d rows (quad*4+r), q col (rt*16+mh).
    // Od[rt] = ones^T * P accumulator: every row = denominator for q=mh.
    f32x4 O[2][4];
#pragma unroll
    for (int rt = 0; rt < 2; ++rt)
#pragma unroll
        for (int i = 0; i < 4; ++i) O[rt][i] = (f32x4){0.f, 0.f, 0.f, 0.f};
    f32x4 Od[2];
    Od[0] = (f32x4){0.f, 0.f, 0.f, 0.f};
    Od[1] = (f32x4){0.f, 0.f, 0.f, 0.f};
    const f16x8 onesv = {(f16)1.f, (f16)1.f, (f16)1.f, (f16)1.f,
                         (f16)1.f, (f16)1.f, (f16)1.f, (f16)1.f};

    auto step = [&](const f16* Kb, const f16* Vb, int jt) {
#pragma unroll
        for (int rt = 0; rt < 2; ++rt) {
            // ---- QK^T per nt: 2 MFMA -> raw exp2 -> packed P write
#pragma unroll
            for (int nt = 0; nt < 4; ++nt) {
                f16x8 kf0 = *(const f16x8*)(Kb + phys8(nt * 16 + mh, 0 + quad) * 8);
                f16x8 kf1 = *(const f16x8*)(Kb + phys8(nt * 16 + mh, 4 + quad) * 8);
                f32x4 S = __builtin_amdgcn_mfma_f32_16x16x32_f16(
                    qf[rt][0], kf0, (f32x4){0.f, 0.f, 0.f, 0.f}, 0, 0, 0);
                S = __builtin_amdgcn_mfma_f32_16x16x32_f16(
                    qf[rt][1], kf1, S, 0, 0, 0);
                const float mvl2 = kLog2e * maskb[jt + nt * 16 + mh];
                union { f16 h4[4]; uint2 u; } pk;
#pragma unroll
                for (int r = 0; r < 4; ++r)
                    pk.h4[r] = (f16)fast_exp2(
                        fmaf(S[r], kLog2e, mvl2) + bndr[rt][r]);
                *(uint2*)(PtW + (nt * 16 + mh) * 16 + quad * 4) = pk.u;
            }
            // ---- transpose-read P as PV B-operand: col=q(mh), k=kv contiguous
            f16x4 t0, t1, t2, t3;
            asm volatile(
                "s_waitcnt lgkmcnt(0)\n\t"
                "ds_read_b64_tr_b16 %0, %4\n\t"
                "ds_read_b64_tr_b16 %1, %4 offset:128\n\t"
                "ds_read_b64_tr_b16 %2, %4 offset:1024\n\t"
                "ds_read_b64_tr_b16 %3, %4 offset:1152\n\t"
                "s_waitcnt lgkmcnt(0)"
                : "=&v"(t0), "=&v"(t1), "=&v"(t2), "=&v"(t3)
                : "v"(ptr_tr) : "memory");
            __builtin_amdgcn_sched_barrier(0);
            f16x8 p0 = __builtin_shufflevector(t0, t1, 0, 1, 2, 3, 4, 5, 6, 7);
            f16x8 p1 = __builtin_shufflevector(t2, t3, 0, 1, 2, 3, 4, 5, 6, 7);
            // ---- PV + denominator, all on the matrix pipe
            __builtin_amdgcn_s_setprio(1);
            Od[rt] = __builtin_amdgcn_mfma_f32_16x16x32_f16(
                onesv, p0, Od[rt], 0, 0, 0);
            Od[rt] = __builtin_amdgcn_mfma_f32_16x16x32_f16(
                onesv, p1, Od[rt], 0, 0, 0);
#pragma unroll
            for (int dt = 0; dt < 4; ++dt) {
                f16x8 vf0 = *(const f16x8*)(Vb + phys8(dt * 16 + mh, 0 + quad) * 8);
                f16x8 vf1 = *(const f16x8*)(Vb + phys8(dt * 16 + mh, 4 + quad) * 8);
                O[rt][dt] = __builtin_amdgcn_mfma_f32_16x16x32_f16(
                    vf0, p0, O[rt][dt], 0, 0, 0);
                O[rt][dt] = __builtin_amdgcn_mfma_f32_16x16x32_f16(
                    vf1, p1, O[rt][dt], 0, 0, 0);
            }
            __builtin_amdgcn_s_setprio(0);
        }
    };

    __syncthreads();

    for (int jt = 0; jt < kS; jt += 128) {
        issue(Ks[1], Vs[1]);
        step(Ks[0], Vs[0], jt);
        __syncthreads();
        if (jt + 128 < kS) issue(Ks[0], Vs[0]);
        step(Ks[1], Vs[1], jt + 64);
        __syncthreads();
    }

#pragma unroll
    for (int rt = 0; rt < 2; ++rt) {
        const float inv = 1.0f / Od[rt][0];   // all 4 rows identical
        const int s = q0 + w * 32 + rt * 16 + mh;
        float* orow = out + ((size_t)(bbb * kS + s)) * kH + (h << 6);
#pragma unroll
        for (int dt = 0; dt < 4; ++dt) {
            f32x4 v;
            v[0] = O[rt][dt][0] * inv;
            v[1] = O[rt][dt][1] * inv;
            v[2] = O[rt][dt][2] * inv;
            v[3] = O[rt][dt][3] * inv;
            __builtin_nontemporal_store(v, (f32x4*)(orow + dt * 16 + quad * 4));
        }
    }
}

// ---------------------------------------------------------------------------
extern "C" void kernel_launch(void* const* d_in, const int* in_sizes, int n_in,
                              void* d_out, int out_size, void* d_ws, size_t ws_size,
                              hipStream_t stream) {
    (void)in_sizes; (void)n_in; (void)out_size; (void)ws_size;

    const float* hs   = (const float*)d_in[0];
    const float* mask = (const float*)d_in[1];
    const float* ce   = (const float*)d_in[2];
    const float* Wq   = (const float*)d_in[3];
    const float* bq   = (const float*)d_in[4];
    const float* Wk   = (const float*)d_in[5];
    const float* bk   = (const float*)d_in[6];
    const float* Wv   = (const float*)d_in[7];
    const float* bv   = (const float*)d_in[8];
    const float* Wcq  = (const float*)d_in[9];
    const float* bcq  = (const float*)d_in[10];
    const float* Wck  = (const float*)d_in[11];
    const float* bck  = (const float*)d_in[12];
    const float* wlqc = (const float*)d_in[13];
    const float* wlqq = (const float*)d_in[14];
    const float* wlkc = (const float*)d_in[15];
    const float* wlkk = (const float*)d_in[16];
    float* out = (float*)d_out;

    f16* hs16 = (f16*)d_ws;                            // 16.78 MB
    f16* Wt   = hs16 + (size_t)kB * kS * kH;           // 6.29 MB
    f16* q16  = Wt + (size_t)3 * kH * kH;              // 16.78 MB
    f16* k16  = q16 + (size_t)kRows * kHD;             // 16.78 MB
    f16* vt   = k16 + (size_t)kRows * kHD;             // 16.78 MB  [bh][d][s]
    f16* Wct  = vt + (size_t)kRows * kHD;              // 16 KB (ce16 deleted)
    unsigned int* kn = (unsigned int*)(Wct + 2 * kHD * kHD);  // 128 u32
    float* mm = (float*)(kn + kBH);                    // 8 f32

    prep_all_kernel<<<dim3(4874), 256, 0, stream>>>(
        hs, Wq, Wk, Wv, Wcq, Wck, mask,
        hs16, Wt, Wct, kn, mm);

    qkv_gemm_f16<<<dim3(kB * kS / 128, kH / 128, 3), 256, 0, stream>>>(
        hs16, Wt, bq, bk, bv, q16, k16, vt,
        ce, Wct, bcq, bck, wlqc, wlqq, wlkc, wlkk, kn);

    attn_f16<<<dim3(kBH, kS / 128), 256, 0, stream>>>(
        q16, k16, vt, mask, kn, mm, out);
}

// Round 15
// 268.052 us; speedup vs baseline: 1.0105x; 1.0027x over previous
//
#include <hip/hip_runtime.h>

typedef _Float16 f16;
typedef f16   f16x8 __attribute__((ext_vector_type(8)));
typedef f16   f16x4 __attribute__((ext_vector_type(4)));
typedef float f32x4 __attribute__((ext_vector_type(4)));

namespace {
constexpr int kB  = 8;
constexpr int kS  = 1024;
constexpr int kH  = 1024;
constexpr int kNH = 16;
constexpr int kHD = 64;
constexpr int kBH = kB * kNH;            // 128
constexpr int kRows = kBH * kS;          // 131072
constexpr float kLog2e = 1.44269504088896f;
}

// Raw hardware 2^x (v_exp_f32).  Round-9 lesson: plain exp2f lowers to the
// OCML precise version (denormal fixup, ~8 ops + branch) without fast-math;
// __expf is the native 2-op path.
__device__ __forceinline__ float fast_exp2(float x) {
#if __has_builtin(__builtin_amdgcn_exp2f)
    return __builtin_amdgcn_exp2f(x);
#else
    return __expf(x * 0.693147180559945f);   // exp(x*ln2) == 2^x, native path
#endif
}

// async global->LDS, 16B per lane; LDS dest = wave-uniform base + lane*16.
// NOTE: only offset=0 is used — the offset immediate's LDS-vs-global
// semantics are unverified on gfx950 (round-4 NaN post-mortem).
__device__ __forceinline__ void async16(const f16* g, f16* l) {
    __builtin_amdgcn_global_load_lds(
        (const __attribute__((address_space(1))) unsigned int*)g,
        (__attribute__((address_space(3))) unsigned int*)l, 16, 0, 0);
}

// --- LDS chunk swizzles (16B chunks). Uniform bank-slot histogram per quad
// for MFMA fragment reads; invertible for global_load_lds staging. ---
__device__ __forceinline__ int phys4(int m, int c) {
    return ((m >> 1) << 3) | ((((m & 1) << 2) | c) ^ ((m >> 1) & 7));
}
__device__ __forceinline__ int phys8(int m, int c) {
    return (m << 3) | (c ^ (m & 7));
}

// ---------------------------------------------------------------------------
// Preprocessing, ONE launch (ce cast plane deleted in round 19).
//   blocks [0,4096):    cast hs fp32 -> f16 flat
//   blocks [4096,4864): transpose Wq/Wk/Wv fp32 [K][N] -> f16 [N][K]
//   blocks [4864,4874): Wcq/Wck transpose-cast + kn zero + mask max
// ---------------------------------------------------------------------------
__global__ __launch_bounds__(256) void prep_all_kernel(
    const float* __restrict__ hs,
    const float* __restrict__ Wq, const float* __restrict__ Wk,
    const float* __restrict__ Wv, const float* __restrict__ Wcq,
    const float* __restrict__ Wck, const float* __restrict__ mask,
    f16* __restrict__ hs16, f16* __restrict__ Wt,
    f16* __restrict__ Wct, unsigned int* __restrict__ kn,
    float* __restrict__ mm)
{
    const int id = blockIdx.x;
    const int t = threadIdx.x;
    __shared__ f16 T[64][72];
    __shared__ float red[4];

    if (id < 4096) {
        // ---- hs cast, flat ----
        int i = (id * 256 + t) * 8;
        float4 a = *(const float4*)(hs + i);
        float4 b = *(const float4*)(hs + i + 4);
        union { f16 h[8]; uint4 u; } pk;
        pk.h[0] = (f16)a.x; pk.h[1] = (f16)a.y; pk.h[2] = (f16)a.z; pk.h[3] = (f16)a.w;
        pk.h[4] = (f16)b.x; pk.h[5] = (f16)b.y; pk.h[6] = (f16)b.z; pk.h[7] = (f16)b.w;
        *(uint4*)(hs16 + i) = pk.u;
    } else if (id < 4864) {
        // ---- W transpose+cast ----
        const int tt = id - 4096;
        const int bx = tt & 15, by = (tt >> 4) & 15, bz = tt >> 8;
        const float* W = (bz == 0) ? Wq : (bz == 1) ? Wk : Wv;
        f16* out = Wt + (size_t)bz * kH * kH;
        const int k0 = by * 64, n0 = bx * 64;
#pragma unroll
        for (int i = 0; i < 4; ++i) {
            int idx = t + i * 256;
            int r = idx >> 4, cb = (idx & 15) * 4;
            float4 v = *(const float4*)(W + (size_t)(k0 + r) * kH + n0 + cb);
            T[cb + 0][r] = (f16)v.x; T[cb + 1][r] = (f16)v.y;
            T[cb + 2][r] = (f16)v.z; T[cb + 3][r] = (f16)v.w;
        }
        __syncthreads();
#pragma unroll
        for (int i = 0; i < 4; ++i) {
            int idx = t + i * 256;
            int r = idx >> 4, cb = (idx & 15) * 4;
            union { f16 h[4]; uint2 u; } pk;
#pragma unroll
            for (int j = 0; j < 4; ++j) pk.h[j] = T[r][cb + j];
            *(uint2*)(out + (size_t)(n0 + r) * kH + k0 + cb) = pk.u;
        }
    } else {
        // ---- small prep ----
        const int bx = id - 4864;
        if (bx < 2) {
            const float* W = bx ? Wck : Wcq;
            f16* out = Wct + bx * kHD * kHD;
#pragma unroll
            for (int i = 0; i < 16; ++i) {
                int idx = i * 256 + t;
                int k = idx >> 6, n = idx & 63;
                out[n * 64 + k] = (f16)W[idx];
            }
            if (bx == 0 && t < kBH) kn[t] = 0u;
        } else {
            const int b = bx - 2;
            const float* mp = mask + b * kS;
            float v = fmaxf(fmaxf(mp[t], mp[t + 256]), fmaxf(mp[t + 512], mp[t + 768]));
#pragma unroll
            for (int off = 1; off < 64; off <<= 1) v = fmaxf(v, __shfl_xor(v, off, 64));
            if ((t & 63) == 0) red[t >> 6] = v;
            __syncthreads();
            if (t == 0) mm[b] = fmaxf(fmaxf(red[0], red[1]), fmaxf(red[2], red[3]));
        }
    }
}

// ---------------------------------------------------------------------------
// QKV GEMM + FUSED CONTEXT GATING.  Round 20: the raw-ce epilogue loads
// are SOFTWARE-PIPELINED one mt ahead — round 19's +24.5 µs regression was
// the serial chain {4 strided fp32 loads -> cvt -> MFMA -> blend} x4 with
// fully exposed L2 latency.  Now mt+1's loads issue right after mt's cvts
// (c-regs dead) and fly under mt's ~150-cycle MFMA+blend phase; only the
// mt=0 loads remain exposed.  +16 transient VGPRs (peak ~164 < 170 cap).
// ---------------------------------------------------------------------------
__global__ __launch_bounds__(256, 3) void qkv_gemm_f16(
    const f16* __restrict__ hs16, const f16* __restrict__ Wt,
    const float* __restrict__ bq, const float* __restrict__ bk,
    const float* __restrict__ bv,
    f16* __restrict__ q16, f16* __restrict__ k16, f16* __restrict__ vt,
    const float* __restrict__ ce, const f16* __restrict__ Wct,
    const float* __restrict__ bcq, const float* __restrict__ bck,
    const float* __restrict__ wlqc, const float* __restrict__ wlqq,
    const float* __restrict__ wlkc, const float* __restrict__ wlkk,
    unsigned int* __restrict__ kn)
{
    const int z = blockIdx.z;
    const f16* Bmat = Wt + (size_t)z * kH * kH;
    const float* bias = (z == 0) ? bq : (z == 1) ? bk : bv;

    __shared__ f16 AB[2][2][128 * 32];   // [buf][A=0/B=1]

    const int tid = threadIdx.x;
    const int w = tid >> 6, lane = tid & 63;
    const int quad = lane >> 4, mh = lane & 15;
    const int wm = w >> 1, wn = w & 1;
    const int m0 = blockIdx.x * 128, n0 = blockIdx.y * 128;

    // A staging pointers (per-lane); B address = A address + block-uniform delta
    const f16* aptr[2];
#pragma unroll
    for (int i = 0; i < 2; ++i) {
        int P = (w * 2 + i) * 64 + lane;
        int r2 = P >> 3, s = P & 7;
        int bb = s ^ (r2 & 7);
        int m = (r2 << 1) | (bb >> 2), c = bb & 3;
        aptr[i] = hs16 + (size_t)(m0 + m) * kH + c * 8;
    }
    const ptrdiff_t bdelta = (Bmat + (size_t)n0 * kH) - (hs16 + (size_t)m0 * kH);

    auto issue = [&](int buf) {
#pragma unroll
        for (int i = 0; i < 2; ++i) {
            async16(aptr[i], AB[buf][0] + (w * 2 + i) * 512);
            async16(aptr[i] + bdelta, AB[buf][1] + (w * 2 + i) * 512);
            aptr[i] += 32;
        }
    };

    f32x4 acc[4][4];
#pragma unroll
    for (int i = 0; i < 4; ++i)
#pragma unroll
        for (int j = 0; j < 4; ++j) acc[i][j] = (f32x4){0.f, 0.f, 0.f, 0.f};

    // fragment base offsets; tile t adds +512 elements (phys4 linearity)
    const int aoff0 = phys4(wm * 64 + mh, quad) * 8;
    const int boff0 = phys4(wn * 64 + mh, quad) * 8;

    auto compute = [&](int buf) {
        f16x8 af[4], bf[4];
#pragma unroll
        for (int t = 0; t < 4; ++t)
            af[t] = *(const f16x8*)(AB[buf][0] + aoff0 + t * 512);
#pragma unroll
        for (int t = 0; t < 4; ++t)
            bf[t] = *(const f16x8*)(AB[buf][1] + boff0 + t * 512);
#pragma unroll
        for (int i = 0; i < 4; ++i)
#pragma unroll
            for (int j = 0; j < 4; ++j)
                acc[i][j] = __builtin_amdgcn_mfma_f32_16x16x32_f16(
                    af[i], bf[j], acc[i][j], 0, 0, 0);
    };

    issue(0);                 // tile 0
    __syncthreads();

    for (int it = 0; it < 16; ++it) {
        issue(1);             // prefetch tile 2it+1 (overlaps compute)
        compute(0);           // tile 2it
        __syncthreads();      // drain prefetch; buf0 free
        if (it < 15) issue(0);  // prefetch tile 2it+2
        compute(1);           // tile 2it+1
        __syncthreads();
    }

    if (z < 2) {
        // ---- fused gate epilogue (all same-wave; AB is dead -> XB alias) ----
        f16* outp = (z == 0) ? q16 : k16;
        const float* bc   = (z == 0) ? bcq  : bck;
        const float* wlc  = (z == 0) ? wlqc : wlkc;
        const float* wlxp = (z == 0) ? wlqq : wlkk;
        const int h   = (n0 + wn * 64) >> 6;
        const int bbb = m0 >> 10;
        const int sb  = (m0 & 1023) + wm * 64;
        const size_t rowbase = (size_t)(bbb * kNH + h) * kS + sb;
        f16* base = outp + rowbase * kHD;
        // raw ce [B,S,H]: row (bbb, sb+r) at ce + (bbb*kS+sb+r)*kH + h*64
        const float* ceb = ce + ((size_t)(bbb * kS + sb)) * kH + (h << 6);
        const f16* Wcg = Wct + (size_t)z * kHD * kHD;

        float bnv[4], bcv[4], wlcv[4], wlxv[4];
#pragma unroll
        for (int nt = 0; nt < 4; ++nt) {
            bnv[nt]  = bias[n0 + wn * 64 + nt * 16 + mh];
            const int d = nt * 16 + mh;
            bcv[nt]  = bc[d];
            wlcv[nt] = wlc[d];
            wlxv[nt] = wlxp[d];
        }
        // B fragments for the ce GEMM (L2-hot 16 KB table; round-14 pattern)
        f16x8 bfr[4][2];
#pragma unroll
        for (int nt = 0; nt < 4; ++nt)
#pragma unroll
            for (int ks = 0; ks < 2; ++ks)
                bfr[nt][ks] = *(const f16x8*)(
                    Wcg + (nt * 16 + mh) * 64 + (ks * 4 + quad) * 8);

        f16* XB = &AB[0][0][0] + w * 4096;   // per-wave 64x64 gated tile

        // ---- pipelined ce loads: mt=0 primed, mt+1 issued after cvt ----
        const float* crow = ceb + (size_t)mh * kH;
        float4 c0 = *(const float4*)(crow + quad * 8);
        float4 c1 = *(const float4*)(crow + quad * 8 + 4);
        float4 c2 = *(const float4*)(crow + 32 + quad * 8);
        float4 c3 = *(const float4*)(crow + 32 + quad * 8 + 4);

#pragma unroll
        for (int mt = 0; mt < 4; ++mt) {
            f16x8 a0 = {(f16)c0.x, (f16)c0.y, (f16)c0.z, (f16)c0.w,
                        (f16)c1.x, (f16)c1.y, (f16)c1.z, (f16)c1.w};
            f16x8 a1 = {(f16)c2.x, (f16)c2.y, (f16)c2.z, (f16)c2.w,
                        (f16)c3.x, (f16)c3.y, (f16)c3.z, (f16)c3.w};
            if (mt < 3) {   // issue next-mt loads; fly under MFMA+blend below
                const float* cnext = ceb + (size_t)((mt + 1) * 16 + mh) * kH;
                c0 = *(const float4*)(cnext + quad * 8);
                c1 = *(const float4*)(cnext + quad * 8 + 4);
                c2 = *(const float4*)(cnext + 32 + quad * 8);
                c3 = *(const float4*)(cnext + 32 + quad * 8 + 4);
            }
            f32x4 accce[4];
#pragma unroll
            for (int nt = 0; nt < 4; ++nt) {
                accce[nt] = __builtin_amdgcn_mfma_f32_16x16x32_f16(
                    a0, bfr[nt][0], (f32x4){0.f, 0.f, 0.f, 0.f}, 0, 0, 0);
                accce[nt] = __builtin_amdgcn_mfma_f32_16x16x32_f16(
                    a1, bfr[nt][1], accce[nt], 0, 0, 0);
            }
#pragma unroll
            for (int r = 0; r < 4; ++r) {
                f16 x16[4], cq16[4];
                float t = 0.f;
#pragma unroll
                for (int nt = 0; nt < 4; ++nt) {
                    x16[nt] = (f16)(acc[mt][nt][r] + bnv[nt]);
                    const float vq = accce[nt][r] + bcv[nt];
                    cq16[nt] = (f16)vq;
                    t += (float)x16[nt] * wlxv[nt] + vq * wlcv[nt];
                }
                t += __shfl_xor(t, 1, 64);
                t += __shfl_xor(t, 2, 64);
                t += __shfl_xor(t, 4, 64);
                t += __shfl_xor(t, 8, 64);
                const float lam = 1.0f / (1.0f + __expf(-t));
                const int row = mt * 16 + quad * 4 + r;
#pragma unroll
                for (int nt = 0; nt < 4; ++nt) {
                    const int blk = (nt * 2 + (mh >> 3)) ^ (row & 7);
                    XB[row * 64 + (blk << 3) + (mh & 7)] =
                        (f16)((1.0f - lam) * (float)x16[nt] +
                              lam * (float)cq16[nt]);
                }
            }
        }
        // coalesced store (+ z==1: per-row |k|^2 max -> kn[bh])
        float wmax = 0.f;
#pragma unroll
        for (int p = 0; p < 8; ++p) {
            const int row = (lane >> 3) + p * 8;
            const int blk = (lane & 7) ^ (row & 7);
            union { uint4 u; f16 hh[8]; } v;
            v.u = *(const uint4*)(XB + row * 64 + (blk << 3));
            *(uint4*)(base + (size_t)row * kHD + (lane & 7) * 8) = v.u;
            if (z == 1) {
                float ss = 0.f;
#pragma unroll
                for (int j = 0; j < 8; ++j) {
                    const float f = (float)v.hh[j];
                    ss += f * f;
                }
                ss += __shfl_xor(ss, 1, 64);
                ss += __shfl_xor(ss, 2, 64);
                ss += __shfl_xor(ss, 4, 64);
                wmax = fmaxf(wmax, ss);
            }
        }
        if (z == 1) {
            wmax = fmaxf(wmax, __shfl_xor(wmax, 8, 64));
            wmax = fmaxf(wmax, __shfl_xor(wmax, 16, 64));
            wmax = fmaxf(wmax, __shfl_xor(wmax, 32, 64));
            if (lane == 0) atomicMax(&kn[bbb * kNH + h], __float_as_uint(wmax));
        }
    } else {
#pragma unroll
        for (int nt = 0; nt < 4; ++nt) {
            const int n = n0 + wn * 64 + nt * 16 + mh;
            const int h = n >> 6, d = n & 63;
            const float bn = bias[n];
#pragma unroll
            for (int mt = 0; mt < 4; ++mt) {
                int mbase = m0 + wm * 64 + mt * 16 + quad * 4;
                int bbb = mbase >> 10, s0 = mbase & 1023;
                union { f16 h4[4]; uint2 u; } pk;
#pragma unroll
                for (int r = 0; r < 4; ++r) pk.h4[r] = (f16)(acc[mt][nt][r] + bn);
                *(uint2*)(vt + ((size_t)(bbb * kNH + h) * kHD + d) * kS + s0) = pk.u;
            }
        }
    }
}

// ---------------------------------------------------------------------------
// MFMA flash attention (round-11 version, best measured; exp2-domain via
// raw v_exp_f32; denominator on matrix pipe; verified absmax 0.001953125).
// ---------------------------------------------------------------------------
__global__ __launch_bounds__(256, 4) void attn_f16(
    const f16* __restrict__ q16, const f16* __restrict__ k16,
    const f16* __restrict__ vt, const float* __restrict__ mask,
    const unsigned int* __restrict__ kn, const float* __restrict__ mm,
    float* __restrict__ out)
{
    __shared__ f16 Ks[2][64 * 64];
    __shared__ f16 Vs[2][64 * 64];
    __shared__ f16 Pt[4][64 * 16];   // per-wave [kv][q16], reused per rt pass

    const int tid = threadIdx.x;
    const int w = tid >> 6, lane = tid & 63;
    const int quad = lane >> 4, mh = lane & 15;
    const int bh = blockIdx.x, bbb = bh >> 4, h = bh & 15;
    const int q0 = blockIdx.y * 128;
    const float* maskb = mask + bbb * kS;

    int mS[2], cS[2];
#pragma unroll
    for (int i = 0; i < 2; ++i) {
        int P = (w * 2 + i) * 64 + lane;
        mS[i] = P >> 3;
        cS[i] = (P & 7) ^ (mS[i] & 7);
    }
    const f16* kp[2]; const f16* vp[2];
#pragma unroll
    for (int i = 0; i < 2; ++i) {
        kp[i] = k16 + ((size_t)bh * kS + mS[i]) * kHD + cS[i] * 8;
        vp[i] = vt  + ((size_t)bh * kHD + mS[i]) * kS + cS[i] * 8;
    }

    auto issue = [&](f16* Kb, f16* Vb) {
#pragma unroll
        for (int i = 0; i < 2; ++i) {
            async16(kp[i], Kb + (w * 2 + i) * 512);
            async16(vp[i], Vb + (w * 2 + i) * 512);
            kp[i] += 64 * kHD;
            vp[i] += 64;
        }
    };

    issue(Ks[0], Vs[0]);

    f16* PtW = &Pt[w][0];
    // AS3 address for tr-reads: group g reads rows g*8+{0..3} of the
    // [64][16] f16 row-major tile (lane addr = base + quad*256B + mh*8B;
    // +128B imm = +4 rows, +1024B imm = +32 rows for the ks=1 slice).
    const __attribute__((address_space(3))) f16* ptr_tr =
        (const __attribute__((address_space(3))) f16*)PtW + quad * 128 + mh * 4;

    f16x8 qf[2][2];
#pragma unroll
    for (int rt = 0; rt < 2; ++rt) {
        const f16* qrow = q16 + ((size_t)bh * kS + q0 + w * 32 + rt * 16 + mh) * kHD;
#pragma unroll
        for (int ks = 0; ks < 2; ++ks) {
            qf[rt][ks] = *(const f16x8*)(qrow + ks * 32 + quad * 8);
#pragma unroll
            for (int j = 0; j < 8; ++j) qf[rt][ks][j] *= (f16)0.125f;
        }
    }

    const float kn2 = __uint_as_float(kn[bh]);
    const float mmb = mm[bbb];
    float bndr[2][4];   // pre-scaled: -log2e * (bound)
#pragma unroll
    for (int rt = 0; rt < 2; ++rt) {
        float qn2 = 0.f;
#pragma unroll
        for (int ks = 0; ks < 2; ++ks)
#pragma unroll
            for (int j = 0; j < 8; ++j) {
                float v = (float)qf[rt][ks][j];
                qn2 += v * v;
            }
        qn2 += __shfl_xor(qn2, 16, 64);
        qn2 += __shfl_xor(qn2, 32, 64);
        const float bnd = sqrtf(qn2 * kn2) + mmb - 9.5f;
#pragma unroll
        for (int r = 0; r < 4; ++r)
            bndr[rt][r] = -kLog2e * __shfl(bnd, quad * 4 + r, 64);
    }

    // O is TRANSPOSED: O[rt][dt] holds d rows (quad*4+r), q col (rt*16+mh).
    // Od[rt] = ones^T * P accumulator: every row = denominator for q=mh.
    f32x4 O[2][4];
#pragma unroll
    for (int rt = 0; rt < 2; ++rt)
#pragma unroll
        for (int i = 0; i < 4; ++i) O[rt][i] = (f32x4){0.f, 0.f, 0.f, 0.f};
    f32x4 Od[2];
    Od[0] = (f32x4){0.f, 0.f, 0.f, 0.f};
    Od[1] = (f32x4){0.f, 0.f, 0.f, 0.f};
    const f16x8 onesv = {(f16)1.f, (f16)1.f, (f16)1.f, (f16)1.f,
                         (f16)1.f, (f16)1.f, (f16)1.f, (f16)1.f};

    auto step = [&](const f16* Kb, const f16* Vb, int jt) {
#pragma unroll
        for (int rt = 0; rt < 2; ++rt) {
            // ---- QK^T per nt: 2 MFMA -> raw exp2 -> packed P write
#pragma unroll
            for (int nt = 0; nt < 4; ++nt) {
                f16x8 kf0 = *(const f16x8*)(Kb + phys8(nt * 16 + mh, 0 + quad) * 8);
                f16x8 kf1 = *(const f16x8*)(Kb + phys8(nt * 16 + mh, 4 + quad) * 8);
                f32x4 S = __builtin_amdgcn_mfma_f32_16x16x32_f16(
                    qf[rt][0], kf0, (f32x4){0.f, 0.f, 0.f, 0.f}, 0, 0, 0);
                S = __builtin_amdgcn_mfma_f32_16x16x32_f16(
                    qf[rt][1], kf1, S, 0, 0, 0);
                const float mvl2 = kLog2e * maskb[jt + nt * 16 + mh];
                union { f16 h4[4]; uint2 u; } pk;
#pragma unroll
                for (int r = 0; r < 4; ++r)
                    pk.h4[r] = (f16)fast_exp2(
                        fmaf(S[r], kLog2e, mvl2) + bndr[rt][r]);
                *(uint2*)(PtW + (nt * 16 + mh) * 16 + quad * 4) = pk.u;
            }
            // ---- transpose-read P as PV B-operand: col=q(mh), k=kv contiguous
            f16x4 t0, t1, t2, t3;
            asm volatile(
                "s_waitcnt lgkmcnt(0)\n\t"
                "ds_read_b64_tr_b16 %0, %4\n\t"
                "ds_read_b64_tr_b16 %1, %4 offset:128\n\t"
                "ds_read_b64_tr_b16 %2, %4 offset:1024\n\t"
                "ds_read_b64_tr_b16 %3, %4 offset:1152\n\t"
                "s_waitcnt lgkmcnt(0)"
                : "=&v"(t0), "=&v"(t1), "=&v"(t2), "=&v"(t3)
                : "v"(ptr_tr) : "memory");
            __builtin_amdgcn_sched_barrier(0);
            f16x8 p0 = __builtin_shufflevector(t0, t1, 0, 1, 2, 3, 4, 5, 6, 7);
            f16x8 p1 = __builtin_shufflevector(t2, t3, 0, 1, 2, 3, 4, 5, 6, 7);
            // ---- PV + denominator, all on the matrix pipe
            __builtin_amdgcn_s_setprio(1);
            Od[rt] = __builtin_amdgcn_mfma_f32_16x16x32_f16(
                onesv, p0, Od[rt], 0, 0, 0);
            Od[rt] = __builtin_amdgcn_mfma_f32_16x16x32_f16(
                onesv, p1, Od[rt], 0, 0, 0);
#pragma unroll
            for (int dt = 0; dt < 4; ++dt) {
                f16x8 vf0 = *(const f16x8*)(Vb + phys8(dt * 16 + mh, 0 + quad) * 8);
                f16x8 vf1 = *(const f16x8*)(Vb + phys8(dt * 16 + mh, 4 + quad) * 8);
                O[rt][dt] = __builtin_amdgcn_mfma_f32_16x16x32_f16(
                    vf0, p0, O[rt][dt], 0, 0, 0);
                O[rt][dt] = __builtin_amdgcn_mfma_f32_16x16x32_f16(
                    vf1, p1, O[rt][dt], 0, 0, 0);
            }
            __builtin_amdgcn_s_setprio(0);
        }
    };

    __syncthreads();

    for (int jt = 0; jt < kS; jt += 128) {
        issue(Ks[1], Vs[1]);
        step(Ks[0], Vs[0], jt);
        __syncthreads();
        if (jt + 128 < kS) issue(Ks[0], Vs[0]);
        step(Ks[1], Vs[1], jt + 64);
        __syncthreads();
    }

#pragma unroll
    for (int rt = 0; rt < 2; ++rt) {
        const float inv = 1.0f / Od[rt][0];   // all 4 rows identical
        const int s = q0 + w * 32 + rt * 16 + mh;
        float* orow = out + ((size_t)(bbb * kS + s)) * kH + (h << 6);
#pragma unroll
        for (int dt = 0; dt < 4; ++dt) {
            f32x4 v;
            v[0] = O[rt][dt][0] * inv;
            v[1] = O[rt][dt][1] * inv;
            v[2] = O[rt][dt][2] * inv;
            v[3] = O[rt][dt][3] * inv;
            __builtin_nontemporal_store(v, (f32x4*)(orow + dt * 16 + quad * 4));
        }
    }
}

// ---------------------------------------------------------------------------
extern "C" void kernel_launch(void* const* d_in, const int* in_sizes, int n_in,
                              void* d_out, int out_size, void* d_ws, size_t ws_size,
                              hipStream_t stream) {
    (void)in_sizes; (void)n_in; (void)out_size; (void)ws_size;

    const float* hs   = (const float*)d_in[0];
    const float* mask = (const float*)d_in[1];
    const float* ce   = (const float*)d_in[2];
    const float* Wq   = (const float*)d_in[3];
    const float* bq   = (const float*)d_in[4];
    const float* Wk   = (const float*)d_in[5];
    const float* bk   = (const float*)d_in[6];
    const float* Wv   = (const float*)d_in[7];
    const float* bv   = (const float*)d_in[8];
    const float* Wcq  = (const float*)d_in[9];
    const float* bcq  = (const float*)d_in[10];
    const float* Wck  = (const float*)d_in[11];
    const float* bck  = (const float*)d_in[12];
    const float* wlqc = (const float*)d_in[13];
    const float* wlqq = (const float*)d_in[14];
    const float* wlkc = (const float*)d_in[15];
    const float* wlkk = (const float*)d_in[16];
    float* out = (float*)d_out;

    f16* hs16 = (f16*)d_ws;                            // 16.78 MB
    f16* Wt   = hs16 + (size_t)kB * kS * kH;           // 6.29 MB
    f16* q16  = Wt + (size_t)3 * kH * kH;              // 16.78 MB
    f16* k16  = q16 + (size_t)kRows * kHD;             // 16.78 MB
    f16* vt   = k16 + (size_t)kRows * kHD;             // 16.78 MB  [bh][d][s]
    f16* Wct  = vt + (size_t)kRows * kHD;              // 16 KB (ce16 deleted)
    unsigned int* kn = (unsigned int*)(Wct + 2 * kHD * kHD);  // 128 u32
    float* mm = (float*)(kn + kBH);                    // 8 f32

    prep_all_kernel<<<dim3(4874), 256, 0, stream>>>(
        hs, Wq, Wk, Wv, Wcq, Wck, mask,
        hs16, Wt, Wct, kn, mm);

    qkv_gemm_f16<<<dim3(kB * kS / 128, kH / 128, 3), 256, 0, stream>>>(
        hs16, Wt, bq, bk, bv, q16, k16, vt,
        ce, Wct, bcq, bck, wlqc, wlqq, wlkc, wlkk, kn);

    attn_f16<<<dim3(kBH, kS / 128), 256, 0, stream>>>(
        q16, k16, vt, mask, kn, mm, out);
}